// Round 15
// baseline (2438.685 us; speedup 1.0000x reference)
//
#include <hip/hip_runtime.h>
#include <hip/hip_fp16.h>

#define DEVFN __device__ __forceinline__

typedef _Float16 v2h __attribute__((ext_vector_type(2)));

DEVFN float fdot2(v2h a, v2h b, float c) {
#if __has_builtin(__builtin_amdgcn_fdot2)
  return __builtin_amdgcn_fdot2(a, b, c, false);
#else
  return c + (float)a[0] * (float)b[0] + (float)a[1] * (float)b[1];
#endif
}

// ---------------------------------------------------------------- utilities
struct OpSum { DEVFN float operator()(float a, float b) const { return a + b; } };

template<int CH, int D, typename OP, int NV>
DEVFN void halve(float (&v)[NV], int lane, int& base) {
  if constexpr (D >= 1) {
    OP op;
    if constexpr (CH > 1) {
      constexpr int H = CH / 2;
      #pragma unroll
      for (int i = 0; i < H; ++i) {
        float send = (lane & D) ? v[i] : v[H + i];
        float r = __shfl_xor(send, D);
        float keep = (lane & D) ? v[H + i] : v[i];
        v[i] = op(keep, r);
      }
      if (lane & D) base += H;
      halve<H, (D >> 1), OP, NV>(v, lane, base);
    } else {
      v[0] = op(v[0], __shfl_xor(v[0], D));
      halve<CH, (D >> 1), OP, NV>(v, lane, base);
    }
  }
}

// Multiplicity-weighted sum + sumsq of a[0..CC) across T threads.
template<int CC, int NA, int T>
DEVFN void do_stats_w(const float (&a)[NA], float m, int tid, float* spart,
                      float* prow, int statoff) {
  float v[2 * CC];
  #pragma unroll
  for (int j = 0; j < CC; ++j) { float x = a[j]; v[2 * j] = m * x; v[2 * j + 1] = m * x * x; }
  int lane = tid & 63, base = 0;
  halve<2 * CC, 32, OpSum, 2 * CC>(v, lane, base);
  int wv = tid >> 6;
  spart[wv * 256 + base] = v[0];
  __syncthreads();
  constexpr int NW = T / 64;
  if (tid < 2 * CC) {
    float s2 = 0.f;
    #pragma unroll
    for (int w = 0; w < NW; ++w) s2 += spart[w * 256 + tid];
    prow[statoff + tid] = s2;
  }
  __syncthreads();
}

// ---------------------------------------------------------------- FPS (structural floor)
__global__ __launch_bounds__(512) void fps_kernel(const float* __restrict__ pts,
                                                  float4* __restrict__ cent) {
  const int b = blockIdx.x, t = threadIdx.x;
  const int wv = t >> 6;
  __shared__ unsigned long long sk2[2][8];
  __shared__ float4 sc4[2][8];
  __shared__ float4 scent[1024];
  const float* p = pts + (size_t)b * 8192 * 3;
  float px[16], py[16], pz[16], dd[16];
  #pragma unroll
  for (int j = 0; j < 16; ++j) {
    const int i = t + j * 512;
    px[j] = p[i * 3]; py[j] = p[i * 3 + 1]; pz[j] = p[i * 3 + 2];
    dd[j] = 1e10f;
  }
  float cx = p[0], cy = p[1], cz = p[2];
  for (int it = 0; it < 1024; ++it) {
    if (t == 0) scent[it] = make_float4(cx, cy, cz, 0.f);
    const int par = it & 1;
    float bd = -1.f, bx = 0.f, by = 0.f, bz = 0.f; int bi = 0;
    #pragma unroll
    for (int j = 0; j < 16; ++j) {
      const float dx = px[j] - cx, dy = py[j] - cy, dz = pz[j] - cz;
      float d = fminf(dd[j], dx * dx + dy * dy + dz * dz);
      dd[j] = d;
      if (d > bd) { bd = d; bi = t + j * 512; bx = px[j]; by = py[j]; bz = pz[j]; }
    }
    float wmax = bd;
    #pragma unroll
    for (int m = 32; m >= 1; m >>= 1) wmax = fmaxf(wmax, __shfl_xor(wmax, m));
    const unsigned long long am = __ballot(bd == wmax);
    bool iswin;
    if (__popcll(am) == 1) {
      iswin = (bd == wmax);
    } else {
      int cand = (bd == wmax) ? bi : 0x7FFFFFFF;
      #pragma unroll
      for (int m = 32; m >= 1; m >>= 1) cand = min(cand, __shfl_xor(cand, m));
      iswin = (bd == wmax) && (bi == cand);
    }
    if (iswin) {
      sk2[par][wv] = ((unsigned long long)__float_as_uint(bd) << 32)
                     | (0xFFFFFFFFu - (unsigned)bi);
      sc4[par][wv] = make_float4(bx, by, bz, 0.f);
    }
    __syncthreads();
    unsigned long long gk = sk2[par][0];
    float4 c4 = sc4[par][0];
    #pragma unroll
    for (int w = 1; w < 8; ++w) {
      const unsigned long long k2 = sk2[par][w];
      const float4 cc = sc4[par][w];
      if (k2 > gk) { gk = k2; c4 = cc; }
    }
    cx = c4.x; cy = c4.y; cz = c4.z;
  }
  __syncthreads();
  #pragma unroll
  for (int i = t; i < 1024; i += 512) cent[(size_t)b * 1024 + i] = scent[i];
}

// ---------------------------------------------------------------- kNN + fused hist + fused moments
// One wave per query; sorted top-64 via sequential sorted-insertion. After
// the scan, lane l holds the l-th nearest (same lane<->k mapping as the old
// moments kernel): do the 16/32/64 shuffle-prefix moments + multiplicity
// histogram here, deleting two kernels.
__global__ __launch_bounds__(256) void knn_kernel(const float* __restrict__ pts,
                                                  const float4* __restrict__ cent,
                                                  int* __restrict__ knn,
                                                  int* __restrict__ cnt,
                                                  float* __restrict__ mpart) {
  __shared__ float smom[4][27];
  const int tid = threadIdx.x;
  const int wv = tid >> 6;
  const int wid = blockIdx.x * 4 + wv;
  const int lane = tid & 63;
  const int b = wid >> 10;
  const float4 q = cent[wid];
  const float q2 = q.x * q.x + q.y * q.y + q.z * q.z;
  const float* p = pts + (size_t)b * 8192 * 3;
  unsigned long long R = ~0ull;
  for (int c0 = 0; c0 < 8192; c0 += 64) {
    const int i = c0 + lane;
    const float x = p[i * 3], y = p[i * 3 + 1], z = p[i * 3 + 2];
    const float p2 = x * x + y * y + z * z;
    const float dot = q.x * x + q.y * y + q.z * z;
    float d2 = q2 - 2.f * dot + p2;
    d2 = fmaxf(d2, 0.f);
    unsigned u = __float_as_uint(d2);
    u = (u & 0x80000000u) ? ~u : (u | 0x80000000u);
    const unsigned long long key = ((unsigned long long)u << 32) | (unsigned)i;
    const unsigned long long rmax = __shfl(R, 63);
    unsigned long long mask = __ballot(key < rmax);
    while (mask) {
      const int src = __ffsll(mask) - 1;
      mask &= mask - 1;
      const unsigned long long nk = __shfl(key, src);
      const int pos = __popcll(__ballot(R < nk));
      if (pos < 64) {
        const unsigned long long Rm1 = __shfl_up(R, 1);
        R = (lane < pos) ? R : (lane == pos ? nk : Rm1);
      }
    }
  }
  const int nidx = (int)(R & 0xffffffffu);
  knn[wid * 64 + lane] = nidx;

  // fused histogram (integer atomics -> deterministic)
  const int gidx = b * 8192 + nidx;
  atomicAdd(&cnt[131072 + gidx], 1);
  if (lane < 32) atomicAdd(&cnt[65536 + gidx], 1);
  if (lane < 16) atomicAdd(&cnt[gidx], 1);

  // fused moments (identical structure to the old moments_kernel)
  const float* pp = pts + (size_t)gidx * 3;
  const float x = pp[0], y = pp[1], z = pp[2];
  float g[9] = {x, y, z, x * x, x * y, x * z, y * y, y * z, z * z};
  #pragma unroll
  for (int m = 8; m >= 1; m >>= 1) {
    #pragma unroll
    for (int i = 0; i < 9; ++i) g[i] += __shfl_xor(g[i], m);
  }
  float h[9], tot[9];
  #pragma unroll
  for (int i = 0; i < 9; ++i) h[i] = g[i] + __shfl_xor(g[i], 16);
  #pragma unroll
  for (int i = 0; i < 9; ++i) tot[i] = h[i] + __shfl_xor(h[i], 32);
  if (lane == 0) {
    #pragma unroll
    for (int i = 0; i < 9; ++i) {
      smom[wv][i] = g[i]; smom[wv][9 + i] = h[i]; smom[wv][18 + i] = tot[i];
    }
  }
  __syncthreads();
  if (tid < 27) {
    mpart[blockIdx.x * 32 + tid] =
        smom[0][tid] + smom[1][tid] + smom[2][tid] + smom[3][tid];
  }
}

// ---------------------------------------------------------------- BN0 finalize (all 3 branches)
__global__ __launch_bounds__(256) void finalize0_kernel(const float* __restrict__ mpart,
    const float* __restrict__ w00, const float* __restrict__ b00,
    const float* __restrict__ g00, const float* __restrict__ be00,
    const float* __restrict__ w01, const float* __restrict__ b01,
    const float* __restrict__ g01, const float* __restrict__ be01,
    const float* __restrict__ w02, const float* __restrict__ b02,
    const float* __restrict__ g02, const float* __restrict__ be02,
    float* __restrict__ scsh) {
  __shared__ float fsum[8][32];
  __shared__ float mom[32];
  const int t = threadIdx.x;
  const int col = t & 31, chunk = t >> 5;
  float s = 0.f;
  for (int r = chunk * 256; r < chunk * 256 + 256; ++r) s += mpart[r * 32 + col];
  fsum[chunk][col] = s;
  __syncthreads();
  if (t < 32) {
    float s2 = 0.f;
    #pragma unroll
    for (int c = 0; c < 8; ++c) s2 += fsum[c][t];
    mom[t] = s2;
  }
  __syncthreads();
  int o; const float *w, *bb, *gg, *be; float E; int base, br;
  if (t < 32)       { br = 0; o = t;      w = w00; bb = b00; gg = g00; be = be00; E = 131072.f; base = 0; }
  else if (t < 96)  { br = 1; o = t - 32; w = w01; bb = b01; gg = g01; be = be01; E = 262144.f; base = 9; }
  else if (t < 160) { br = 2; o = t - 96; w = w02; bb = b02; gg = g02; be = be02; E = 524288.f; base = 18; }
  else return;
  const float Sx = mom[base], Sy = mom[base + 1], Sz = mom[base + 2];
  const float mxx = mom[base + 3], mxy = mom[base + 4], mxz = mom[base + 5];
  const float myy = mom[base + 6], myz = mom[base + 7], mzz = mom[base + 8];
  const float W0 = w[o * 3], W1 = w[o * 3 + 1], W2 = w[o * 3 + 2], bo = bb[o];
  const float wS = W0 * Sx + W1 * Sy + W2 * Sz;
  const float qf = W0 * W0 * mxx + 2.f * W0 * W1 * mxy + 2.f * W0 * W2 * mxz
                 + W1 * W1 * myy + 2.f * W1 * W2 * myz + W2 * W2 * mzz;
  const float mean = wS / E + bo;
  const float msq = (qf + 2.f * bo * wS) / E + bo * bo;
  const float var = msq - mean * mean;
  const float inv = 1.0f / sqrtf(var + 1e-5f);
  const float sc = gg[o] * inv;
  scsh[br * 768 + o] = sc;
  scsh[br * 768 + 128 + o] = be[o] - mean * sc;
}

// ---------------------------------------------------------------- pack w1/w2 as half2 pairs
__global__ __launch_bounds__(256) void pack_kernel(
    const float* __restrict__ w1a, const float* __restrict__ w1b, const float* __restrict__ w1c,
    const float* __restrict__ w2a, const float* __restrict__ w2b, const float* __restrict__ w2c,
    v2h* __restrict__ w1h2, v2h* __restrict__ w2h2) {
  const int i = blockIdx.x * 256 + threadIdx.x;
  if (i < 512) {                                   // b1 w1: C0=32, C1=32
    const int o = i >> 4, c2 = i & 15;
    w1h2[i] = v2h{(_Float16)w1a[o * 32 + 2 * c2], (_Float16)w1a[o * 32 + 2 * c2 + 1]};
  } else if (i < 2560) {                           // b2 w1: C0=64, C1=64
    const int j = i - 512, o = j >> 5, c2 = j & 31;
    w1h2[i] = v2h{(_Float16)w1b[o * 64 + 2 * c2], (_Float16)w1b[o * 64 + 2 * c2 + 1]};
  } else if (i < 5632) {                           // b3 w1: C0=64, C1=96
    const int j = i - 2560, o = j >> 5, c2 = j & 31;
    w1h2[i] = v2h{(_Float16)w1c[o * 64 + 2 * c2], (_Float16)w1c[o * 64 + 2 * c2 + 1]};
  } else if (i < 6656) {                           // b1 w2: C1=32, C2=64
    const int j = i - 5632, c2 = j >> 6, jj = j & 63;
    w2h2[j] = v2h{(_Float16)w2a[jj * 32 + 2 * c2], (_Float16)w2a[jj * 32 + 2 * c2 + 1]};
  } else if (i < 10752) {                          // b2 w2: C1=64, C2=128
    const int j = i - 6656, c2 = j >> 7, jj = j & 127;
    w2h2[1024 + j] = v2h{(_Float16)w2b[jj * 64 + 2 * c2], (_Float16)w2b[jj * 64 + 2 * c2 + 1]};
  } else if (i < 16896) {                          // b3 w2: C1=96, C2=128
    const int j = i - 10752, c2 = j >> 7, jj = j & 127;
    w2h2[5120 + j] = v2h{(_Float16)w2c[jj * 96 + 2 * c2], (_Float16)w2c[jj * 96 + 2 * c2 + 1]};
  }
}

// ---------------------------------------------------------------- zero (multiplicities)
__global__ __launch_bounds__(256) void zero_kernel(int* __restrict__ p, int n) {
  const int i = blockIdx.x * 256 + threadIdx.x;
  if (i < n) p[i] = 0;
}

// ---------------------------------------------------------------- BN finalize (direct 512-row sum)
__global__ __launch_bounds__(256) void finalize_kernel(const float* __restrict__ partials, int nb,
    const float* __restrict__ g, const float* __restrict__ be, float n,
    float* __restrict__ sc, float* __restrict__ sh, int CO) {
  __shared__ float tot[256];
  const int j = threadIdx.x;
  if (j < 2 * CO) {
    float s = 0.f;
    for (int r = 0; r < nb; ++r) s += partials[(size_t)r * 256 + j];
    tot[j] = s;
  }
  __syncthreads();
  if (j < CO) {
    const float m = tot[2 * j] / n;
    const float v = tot[2 * j + 1] / n - m * m;
    const float inv = 1.0f / sqrtf(v + 1e-5f);
    const float scv = g[j] * inv;
    sc[j] = scv;
    sh[j] = be[j] - m * scv;
  }
}

// ---------------------------------------------------------------- pass1: distinct points, L0+BN0+L1
template<int C0, int C1, int T>
__global__ __launch_bounds__(T) void pass1_kernel(
    const float* __restrict__ pts, const int* __restrict__ cnt,
    const float* __restrict__ w0, const float* __restrict__ b0,
    const v2h* __restrict__ w1p, const float* __restrict__ b1,
    const float* __restrict__ scshb, float* __restrict__ partials,
    __half2* __restrict__ x1h2) {
  constexpr int C02 = C0 / 2;
  __shared__ float spart[(T / 64) * 256];
  const int tid = threadIdx.x;
  const int pt = blockIdx.x * T + tid;
  const float m = (float)cnt[pt];
  const float* pp = pts + (size_t)pt * 3;
  float* prow = partials + (size_t)blockIdx.x * 256;
  const float zx = pp[0], zy = pp[1], zz = pp[2];
  const float* sc0 = scshb;
  const float* sh0 = scshb + 128;
  v2h a0p[C02];
  #pragma unroll
  for (int c2 = 0; c2 < C02; ++c2) {
    float va = b0[2 * c2]     + zx * w0[6 * c2]     + zy * w0[6 * c2 + 1] + zz * w0[6 * c2 + 2];
    float vb = b0[2 * c2 + 1] + zx * w0[6 * c2 + 3] + zy * w0[6 * c2 + 4] + zz * w0[6 * c2 + 5];
    va = fmaxf(0.f, va * sc0[2 * c2] + sh0[2 * c2]);
    vb = fmaxf(0.f, vb * sc0[2 * c2 + 1] + sh0[2 * c2 + 1]);
    a0p[c2] = v2h{(_Float16)va, (_Float16)vb};
  }
  for (int CB = 0; CB < C1; CB += 32) {
    float arr[32];
    #pragma unroll
    for (int oo = 0; oo < 32; ++oo) {
      const int o = CB + oo;
      float s0 = 0.f, s1 = 0.f;
      #pragma unroll
      for (int c2 = 0; c2 < C02; c2 += 2) {
        s0 = fdot2(a0p[c2],     w1p[o * C02 + c2],     s0);
        s1 = fdot2(a0p[c2 + 1], w1p[o * C02 + c2 + 1], s1);
      }
      arr[oo] = b1[o] + (s0 + s1);
    }
    #pragma unroll
    for (int j = 0; j < 16; ++j)
      x1h2[(size_t)(CB / 2 + j) * 65536 + pt] = __floats2half2_rn(arr[2 * j], arr[2 * j + 1]);
    do_stats_w<32, 32, T>(arr, m, tid, spart, prow, 2 * CB);
  }
}

// ---------------------------------------------------------------- pass2: BN1+relu+L2 on distinct points
template<int C1, int C2, int T>
__global__ __launch_bounds__(T) void pass2_kernel(
    const __half2* __restrict__ x1h2, const int* __restrict__ cnt,
    const v2h* __restrict__ w2p, const float* __restrict__ b2,
    const float* __restrict__ scshb, float* __restrict__ partials,
    __half2* __restrict__ x2h2) {
  constexpr int C12 = C1 / 2;
  constexpr int CP = C2 / 2;
  constexpr int RSv = C12 + 1;                   // odd dword stride -> conflict-free
  __shared__ v2h arowv[T * RSv];
  __shared__ float spart[(T / 64) * 256];
  const int tid = threadIdx.x;
  const int pt = blockIdx.x * T + tid;
  const float m = (float)cnt[pt];
  float* prow = partials + (size_t)blockIdx.x * 256;
  const float* sc1 = scshb + 256;
  const float* sh1 = scshb + 384;
  for (int o2 = 0; o2 < C12; ++o2) {
    const float2 f = __half22float2(x1h2[(size_t)o2 * 65536 + pt]);
    const float xa = fmaxf(0.f, f.x * sc1[2 * o2] + sh1[2 * o2]);
    const float xb = fmaxf(0.f, f.y * sc1[2 * o2 + 1] + sh1[2 * o2 + 1]);
    arowv[tid * RSv + o2] = v2h{(_Float16)xa, (_Float16)xb};
  }
  for (int CB = 0; CB < C2; CB += 32) {
    float acc[32];
    #pragma unroll
    for (int j = 0; j < 32; ++j) acc[j] = b2[CB + j];
    for (int c2 = 0; c2 < C12; ++c2) {
      const v2h az = arowv[tid * RSv + c2];
      const v2h* wrow = w2p + c2 * C2 + CB;
      #pragma unroll
      for (int j = 0; j < 32; ++j) acc[j] = fdot2(az, wrow[j], acc[j]);
    }
    #pragma unroll
    for (int j = 0; j < 16; ++j)
      x2h2[(size_t)pt * CP + CB / 2 + j] = __floats2half2_rn(acc[2 * j], acc[2 * j + 1]);
    do_stats_w<32, 32, T>(acc, m, tid, spart, prow, 2 * CB);
  }
}

// ---------------------------------------------------------------- pool: gather-max + BN2 + relu
template<int K_, int C2, int BOFF>
__global__ __launch_bounds__(256) void pool_kernel(const __half2* __restrict__ x2h2,
                                                   const int* __restrict__ knn_,
                                                   const float* __restrict__ scshb,
                                                   float* __restrict__ out) {
  constexpr int CP = C2 / 2;
  const int g = blockIdx.x * 256 + threadIdx.x;  // < 8192 * CP
  const int cp = g % CP;
  const int s = g / CP;
  const int b = s >> 10;
  const int* kn = knn_ + s * 64;
  float mx0 = -1e30f, mx1 = -1e30f, mn0 = 1e30f, mn1 = 1e30f;
  for (int k = 0; k < K_; ++k) {
    const int idx = kn[k];
    const float2 f = __half22float2(x2h2[(size_t)(b * 8192 + idx) * CP + cp]);
    mx0 = fmaxf(mx0, f.x); mn0 = fminf(mn0, f.x);
    mx1 = fmaxf(mx1, f.y); mn1 = fminf(mn1, f.y);
  }
  const float sca = scshb[512 + 2 * cp], scb = scshb[512 + 2 * cp + 1];
  const float sha = scshb[640 + 2 * cp], shb = scshb[640 + 2 * cp + 1];
  float2 r;
  r.x = fmaxf(0.f, fmaf(sca, (sca >= 0.f) ? mx0 : mn0, sha));
  r.y = fmaxf(0.f, fmaf(scb, (scb >= 0.f) ? mx1 : mn1, shb));
  *(float2*)&out[(size_t)s * 320 + BOFF + 2 * cp] = r;
}

// ---------------------------------------------------------------- host side
template<int K_, int C0, int C1, int C2, int BOFF>
static void run_branch(const float* pts, const int* knn_, const int* cntb,
                       const float* const* W_, const float* const* B_,
                       const float* const* G_, const float* const* BE_,
                       float* scshb, float* partials,
                       const v2h* w1pb, const v2h* w2pb,
                       __half2* x1h2, __half2* x2h2, float* out, hipStream_t stream) {
  constexpr int T = 128;
  constexpr int NB = 65536 / T;                  // 512
  const float NEf = (float)(8 * 1024 * K_);
  pass1_kernel<C0, C1, T><<<NB, T, 0, stream>>>(
      pts, cntb, W_[0], B_[0], w1pb, B_[1], scshb, partials, x1h2);
  finalize_kernel<<<1, 256, 0, stream>>>(partials, NB, G_[1], BE_[1], NEf,
                                         scshb + 256, scshb + 384, C1);
  pass2_kernel<C1, C2, T><<<NB, T, 0, stream>>>(
      x1h2, cntb, w2pb, B_[2], scshb, partials, x2h2);
  finalize_kernel<<<1, 256, 0, stream>>>(partials, NB, G_[2], BE_[2], NEf,
                                         scshb + 512, scshb + 640, C2);
  pool_kernel<K_, C2, BOFF><<<8192 * (C2 / 2) / 256, 256, 0, stream>>>(
      x2h2, knn_, scshb, out);
}

extern "C" void kernel_launch(void* const* d_in, const int* in_sizes, int n_in,
                              void* d_out, int out_size, void* d_ws, size_t ws_size,
                              hipStream_t stream) {
  (void)in_sizes; (void)n_in; (void)out_size; (void)ws_size;
  const float* pts = (const float*)d_in[0];
  const float* W_[9]; const float* B_[9]; const float* G_[9]; const float* BE_[9];
  for (int m = 0; m < 9; ++m) {
    W_[m]  = (const float*)d_in[1 + m * 4 + 0];
    B_[m]  = (const float*)d_in[1 + m * 4 + 1];
    G_[m]  = (const float*)d_in[1 + m * 4 + 2];
    BE_[m] = (const float*)d_in[1 + m * 4 + 3];
  }
  char* ws = (char*)d_ws;
  float4*  cent     = (float4*)ws;                          // @0,        131072 B
  int*     knn_     = (int*)(ws + 131072);                  // 2 MB
  float*   partials = (float*)(ws + 2228224);               // 4 MB (also mpart)
  float*   scsh     = (float*)(ws + 6422528);               // 12 KB
  v2h*     w1h2     = (v2h*)(ws + 6434816);                 // 22528 B
  v2h*     w2h2     = (v2h*)(ws + 6457344);                 // 45056 B
  int*     cnt      = (int*)(ws + 6535168);                 // 786432 B (3 x 65536)
  __half2* x1h2     = (__half2*)(ws + 7321600);             // 12582912 B (48 x 65536 x 4)
  __half2* x2h2     = (__half2*)(ws + 19904512);            // 16777216 B (65536 x 64 x 4)
  float*   out      = (float*)d_out;

  zero_kernel<<<768, 256, 0, stream>>>(cnt, 196608);
  fps_kernel<<<8, 512, 0, stream>>>(pts, cent);
  knn_kernel<<<2048, 256, 0, stream>>>(pts, cent, knn_, cnt, partials);
  finalize0_kernel<<<1, 256, 0, stream>>>(partials,
      W_[0], B_[0], G_[0], BE_[0], W_[3], B_[3], G_[3], BE_[3],
      W_[6], B_[6], G_[6], BE_[6], scsh);
  pack_kernel<<<66, 256, 0, stream>>>(W_[1], W_[4], W_[7], W_[2], W_[5], W_[8], w1h2, w2h2);

  run_branch<16, 32, 32, 64, 0>(pts, knn_, cnt, W_ + 0, B_ + 0, G_ + 0, BE_ + 0,
      scsh, partials, w1h2, w2h2, x1h2, x2h2, out, stream);
  run_branch<32, 64, 64, 128, 64>(pts, knn_, cnt + 65536, W_ + 3, B_ + 3, G_ + 3, BE_ + 3,
      scsh + 768, partials, w1h2 + 512, w2h2 + 1024, x1h2, x2h2, out, stream);
  run_branch<64, 64, 96, 128, 192>(pts, knn_, cnt + 131072, W_ + 6, B_ + 6, G_ + 6, BE_ + 6,
      scsh + 1536, partials, w1h2 + 2560, w2h2 + 5120, x1h2, x2h2, out, stream);
}

// Round 16
// 1818.253 us; speedup vs baseline: 1.3412x; 1.3412x over previous
//
#include <hip/hip_runtime.h>
#include <hip/hip_fp16.h>

#define DEVFN __device__ __forceinline__

typedef _Float16 v2h __attribute__((ext_vector_type(2)));

DEVFN float fdot2(v2h a, v2h b, float c) {
#if __has_builtin(__builtin_amdgcn_fdot2)
  return __builtin_amdgcn_fdot2(a, b, c, false);
#else
  return c + (float)a[0] * (float)b[0] + (float)a[1] * (float)b[1];
#endif
}

// ---------------------------------------------------------------- utilities
struct OpSum { DEVFN float operator()(float a, float b) const { return a + b; } };

template<int CH, int D, typename OP, int NV>
DEVFN void halve(float (&v)[NV], int lane, int& base) {
  if constexpr (D >= 1) {
    OP op;
    if constexpr (CH > 1) {
      constexpr int H = CH / 2;
      #pragma unroll
      for (int i = 0; i < H; ++i) {
        float send = (lane & D) ? v[i] : v[H + i];
        float r = __shfl_xor(send, D);
        float keep = (lane & D) ? v[H + i] : v[i];
        v[i] = op(keep, r);
      }
      if (lane & D) base += H;
      halve<H, (D >> 1), OP, NV>(v, lane, base);
    } else {
      v[0] = op(v[0], __shfl_xor(v[0], D));
      halve<CH, (D >> 1), OP, NV>(v, lane, base);
    }
  }
}

// Multiplicity-weighted sum + sumsq of a[0..CC) across T threads.
template<int CC, int NA, int T>
DEVFN void do_stats_w(const float (&a)[NA], float m, int tid, float* spart,
                      float* prow, int statoff) {
  float v[2 * CC];
  #pragma unroll
  for (int j = 0; j < CC; ++j) { float x = a[j]; v[2 * j] = m * x; v[2 * j + 1] = m * x * x; }
  int lane = tid & 63, base = 0;
  halve<2 * CC, 32, OpSum, 2 * CC>(v, lane, base);
  int wv = tid >> 6;
  spart[wv * 256 + base] = v[0];
  __syncthreads();
  constexpr int NW = T / 64;
  if (tid < 2 * CC) {
    float s2 = 0.f;
    #pragma unroll
    for (int w = 0; w < NW; ++w) s2 += spart[w * 256 + tid];
    prow[statoff + tid] = s2;
  }
  __syncthreads();
}

// ---------------------------------------------------------------- FPS (structural floor)
__global__ __launch_bounds__(512) void fps_kernel(const float* __restrict__ pts,
                                                  float4* __restrict__ cent) {
  const int b = blockIdx.x, t = threadIdx.x;
  const int wv = t >> 6;
  __shared__ unsigned long long sk2[2][8];
  __shared__ float4 sc4[2][8];
  __shared__ float4 scent[1024];
  const float* p = pts + (size_t)b * 8192 * 3;
  float px[16], py[16], pz[16], dd[16];
  #pragma unroll
  for (int j = 0; j < 16; ++j) {
    const int i = t + j * 512;
    px[j] = p[i * 3]; py[j] = p[i * 3 + 1]; pz[j] = p[i * 3 + 2];
    dd[j] = 1e10f;
  }
  float cx = p[0], cy = p[1], cz = p[2];
  for (int it = 0; it < 1024; ++it) {
    if (t == 0) scent[it] = make_float4(cx, cy, cz, 0.f);
    const int par = it & 1;
    float bd = -1.f, bx = 0.f, by = 0.f, bz = 0.f; int bi = 0;
    #pragma unroll
    for (int j = 0; j < 16; ++j) {
      const float dx = px[j] - cx, dy = py[j] - cy, dz = pz[j] - cz;
      float d = fminf(dd[j], dx * dx + dy * dy + dz * dz);
      dd[j] = d;
      if (d > bd) { bd = d; bi = t + j * 512; bx = px[j]; by = py[j]; bz = pz[j]; }
    }
    float wmax = bd;
    #pragma unroll
    for (int m = 32; m >= 1; m >>= 1) wmax = fmaxf(wmax, __shfl_xor(wmax, m));
    const unsigned long long am = __ballot(bd == wmax);
    bool iswin;
    if (__popcll(am) == 1) {
      iswin = (bd == wmax);
    } else {
      int cand = (bd == wmax) ? bi : 0x7FFFFFFF;
      #pragma unroll
      for (int m = 32; m >= 1; m >>= 1) cand = min(cand, __shfl_xor(cand, m));
      iswin = (bd == wmax) && (bi == cand);
    }
    if (iswin) {
      sk2[par][wv] = ((unsigned long long)__float_as_uint(bd) << 32)
                     | (0xFFFFFFFFu - (unsigned)bi);
      sc4[par][wv] = make_float4(bx, by, bz, 0.f);
    }
    __syncthreads();
    unsigned long long gk = sk2[par][0];
    float4 c4 = sc4[par][0];
    #pragma unroll
    for (int w = 1; w < 8; ++w) {
      const unsigned long long k2 = sk2[par][w];
      const float4 cc = sc4[par][w];
      if (k2 > gk) { gk = k2; c4 = cc; }
    }
    cx = c4.x; cy = c4.y; cz = c4.z;
  }
  __syncthreads();
  #pragma unroll
  for (int i = t; i < 1024; i += 512) cent[(size_t)b * 1024 + i] = scent[i];
}

// ---------------------------------------------------------------- kNN + fused hist + fused moments
__global__ __launch_bounds__(256) void knn_kernel(const float* __restrict__ pts,
                                                  const float4* __restrict__ cent,
                                                  int* __restrict__ knn,
                                                  int* __restrict__ cnt,
                                                  float* __restrict__ mpart) {
  __shared__ float smom[4][27];
  const int tid = threadIdx.x;
  const int wv = tid >> 6;
  const int wid = blockIdx.x * 4 + wv;
  const int lane = tid & 63;
  const int b = wid >> 10;
  const float4 q = cent[wid];
  const float q2 = q.x * q.x + q.y * q.y + q.z * q.z;
  const float* p = pts + (size_t)b * 8192 * 3;
  unsigned long long R = ~0ull;
  for (int c0 = 0; c0 < 8192; c0 += 64) {
    const int i = c0 + lane;
    const float x = p[i * 3], y = p[i * 3 + 1], z = p[i * 3 + 2];
    const float p2 = x * x + y * y + z * z;
    const float dot = q.x * x + q.y * y + q.z * z;
    float d2 = q2 - 2.f * dot + p2;
    d2 = fmaxf(d2, 0.f);
    unsigned u = __float_as_uint(d2);
    u = (u & 0x80000000u) ? ~u : (u | 0x80000000u);
    const unsigned long long key = ((unsigned long long)u << 32) | (unsigned)i;
    const unsigned long long rmax = __shfl(R, 63);
    unsigned long long mask = __ballot(key < rmax);
    while (mask) {
      const int src = __ffsll(mask) - 1;
      mask &= mask - 1;
      const unsigned long long nk = __shfl(key, src);
      const int pos = __popcll(__ballot(R < nk));
      if (pos < 64) {
        const unsigned long long Rm1 = __shfl_up(R, 1);
        R = (lane < pos) ? R : (lane == pos ? nk : Rm1);
      }
    }
  }
  const int nidx = (int)(R & 0xffffffffu);
  knn[wid * 64 + lane] = nidx;

  // fused histogram (integer atomics -> deterministic)
  const int gidx = b * 8192 + nidx;
  atomicAdd(&cnt[131072 + gidx], 1);
  if (lane < 32) atomicAdd(&cnt[65536 + gidx], 1);
  if (lane < 16) atomicAdd(&cnt[gidx], 1);

  // fused moments (identical structure to the old moments_kernel)
  const float* pp = pts + (size_t)gidx * 3;
  const float x = pp[0], y = pp[1], z = pp[2];
  float g[9] = {x, y, z, x * x, x * y, x * z, y * y, y * z, z * z};
  #pragma unroll
  for (int m = 8; m >= 1; m >>= 1) {
    #pragma unroll
    for (int i = 0; i < 9; ++i) g[i] += __shfl_xor(g[i], m);
  }
  float h[9], tot[9];
  #pragma unroll
  for (int i = 0; i < 9; ++i) h[i] = g[i] + __shfl_xor(g[i], 16);
  #pragma unroll
  for (int i = 0; i < 9; ++i) tot[i] = h[i] + __shfl_xor(h[i], 32);
  if (lane == 0) {
    #pragma unroll
    for (int i = 0; i < 9; ++i) {
      smom[wv][i] = g[i]; smom[wv][9 + i] = h[i]; smom[wv][18 + i] = tot[i];
    }
  }
  __syncthreads();
  if (tid < 27) {
    mpart[blockIdx.x * 32 + tid] =
        smom[0][tid] + smom[1][tid] + smom[2][tid] + smom[3][tid];
  }
}

// ---------------------------------------------------------------- BN0 finalize (all 3 branches)
__global__ __launch_bounds__(256) void finalize0_kernel(const float* __restrict__ mpart,
    const float* __restrict__ w00, const float* __restrict__ b00,
    const float* __restrict__ g00, const float* __restrict__ be00,
    const float* __restrict__ w01, const float* __restrict__ b01,
    const float* __restrict__ g01, const float* __restrict__ be01,
    const float* __restrict__ w02, const float* __restrict__ b02,
    const float* __restrict__ g02, const float* __restrict__ be02,
    float* __restrict__ scsh) {
  __shared__ float fsum[8][32];
  __shared__ float mom[32];
  const int t = threadIdx.x;
  const int col = t & 31, chunk = t >> 5;
  float s = 0.f;
  for (int r = chunk * 256; r < chunk * 256 + 256; ++r) s += mpart[r * 32 + col];
  fsum[chunk][col] = s;
  __syncthreads();
  if (t < 32) {
    float s2 = 0.f;
    #pragma unroll
    for (int c = 0; c < 8; ++c) s2 += fsum[c][t];
    mom[t] = s2;
  }
  __syncthreads();
  int o; const float *w, *bb, *gg, *be; float E; int base, br;
  if (t < 32)       { br = 0; o = t;      w = w00; bb = b00; gg = g00; be = be00; E = 131072.f; base = 0; }
  else if (t < 96)  { br = 1; o = t - 32; w = w01; bb = b01; gg = g01; be = be01; E = 262144.f; base = 9; }
  else if (t < 160) { br = 2; o = t - 96; w = w02; bb = b02; gg = g02; be = be02; E = 524288.f; base = 18; }
  else return;
  const float Sx = mom[base], Sy = mom[base + 1], Sz = mom[base + 2];
  const float mxx = mom[base + 3], mxy = mom[base + 4], mxz = mom[base + 5];
  const float myy = mom[base + 6], myz = mom[base + 7], mzz = mom[base + 8];
  const float W0 = w[o * 3], W1 = w[o * 3 + 1], W2 = w[o * 3 + 2], bo = bb[o];
  const float wS = W0 * Sx + W1 * Sy + W2 * Sz;
  const float qf = W0 * W0 * mxx + 2.f * W0 * W1 * mxy + 2.f * W0 * W2 * mxz
                 + W1 * W1 * myy + 2.f * W1 * W2 * myz + W2 * W2 * mzz;
  const float mean = wS / E + bo;
  const float msq = (qf + 2.f * bo * wS) / E + bo * bo;
  const float var = msq - mean * mean;
  const float inv = 1.0f / sqrtf(var + 1e-5f);
  const float sc = gg[o] * inv;
  scsh[br * 768 + o] = sc;
  scsh[br * 768 + 128 + o] = be[o] - mean * sc;
}

// ---------------------------------------------------------------- pack w1/w2 as half2 pairs
__global__ __launch_bounds__(256) void pack_kernel(
    const float* __restrict__ w1a, const float* __restrict__ w1b, const float* __restrict__ w1c,
    const float* __restrict__ w2a, const float* __restrict__ w2b, const float* __restrict__ w2c,
    v2h* __restrict__ w1h2, v2h* __restrict__ w2h2) {
  const int i = blockIdx.x * 256 + threadIdx.x;
  if (i < 512) {                                   // b1 w1: C0=32, C1=32
    const int o = i >> 4, c2 = i & 15;
    w1h2[i] = v2h{(_Float16)w1a[o * 32 + 2 * c2], (_Float16)w1a[o * 32 + 2 * c2 + 1]};
  } else if (i < 2560) {                           // b2 w1: C0=64, C1=64
    const int j = i - 512, o = j >> 5, c2 = j & 31;
    w1h2[i] = v2h{(_Float16)w1b[o * 64 + 2 * c2], (_Float16)w1b[o * 64 + 2 * c2 + 1]};
  } else if (i < 5632) {                           // b3 w1: C0=64, C1=96
    const int j = i - 2560, o = j >> 5, c2 = j & 31;
    w1h2[i] = v2h{(_Float16)w1c[o * 64 + 2 * c2], (_Float16)w1c[o * 64 + 2 * c2 + 1]};
  } else if (i < 6656) {                           // b1 w2: C1=32, C2=64
    const int j = i - 5632, c2 = j >> 6, jj = j & 63;
    w2h2[j] = v2h{(_Float16)w2a[jj * 32 + 2 * c2], (_Float16)w2a[jj * 32 + 2 * c2 + 1]};
  } else if (i < 10752) {                          // b2 w2: C1=64, C2=128
    const int j = i - 6656, c2 = j >> 7, jj = j & 127;
    w2h2[1024 + j] = v2h{(_Float16)w2b[jj * 64 + 2 * c2], (_Float16)w2b[jj * 64 + 2 * c2 + 1]};
  } else if (i < 16896) {                          // b3 w2: C1=96, C2=128
    const int j = i - 10752, c2 = j >> 7, jj = j & 127;
    w2h2[5120 + j] = v2h{(_Float16)w2c[jj * 96 + 2 * c2], (_Float16)w2c[jj * 96 + 2 * c2 + 1]};
  }
}

// ---------------------------------------------------------------- zero (multiplicities)
__global__ __launch_bounds__(256) void zero_kernel(int* __restrict__ p, int n) {
  const int i = blockIdx.x * 256 + threadIdx.x;
  if (i < n) p[i] = 0;
}

// ---------------------------------------------------------------- stats reduction, stage A
// 32 parallel blocks each sum a fixed 16-row chunk (deterministic).
__global__ __launch_bounds__(256) void reduce_rows_kernel(const float* __restrict__ partials,
                                                          int nb, float* __restrict__ out32) {
  const int r0 = blockIdx.x, j = threadIdx.x;
  const int chunk = (nb + 31) / 32;
  const int lo = r0 * chunk;
  const int hi = (lo + chunk < nb) ? lo + chunk : nb;
  float s = 0.f;
  for (int r = lo; r < hi; ++r) s += partials[(size_t)r * 256 + j];
  out32[r0 * 256 + j] = s;
}

// ---------------------------------------------------------------- BN finalize
__global__ __launch_bounds__(256) void finalize_kernel(const float* __restrict__ partials, int nb,
    const float* __restrict__ g, const float* __restrict__ be, float n,
    float* __restrict__ sc, float* __restrict__ sh, int CO) {
  __shared__ float tot[256];
  const int j = threadIdx.x;
  if (j < 2 * CO) {
    float s = 0.f;
    for (int r = 0; r < nb; ++r) s += partials[(size_t)r * 256 + j];
    tot[j] = s;
  }
  __syncthreads();
  if (j < CO) {
    const float m = tot[2 * j] / n;
    const float v = tot[2 * j + 1] / n - m * m;
    const float inv = 1.0f / sqrtf(v + 1e-5f);
    const float scv = g[j] * inv;
    sc[j] = scv;
    sh[j] = be[j] - m * scv;
  }
}

// ---------------------------------------------------------------- pass1: distinct points, L0+BN0+L1
template<int C0, int C1, int T>
__global__ __launch_bounds__(T) void pass1_kernel(
    const float* __restrict__ pts, const int* __restrict__ cnt,
    const float* __restrict__ w0, const float* __restrict__ b0,
    const v2h* __restrict__ w1p, const float* __restrict__ b1,
    const float* __restrict__ scshb, float* __restrict__ partials,
    __half2* __restrict__ x1h2) {
  constexpr int C02 = C0 / 2;
  __shared__ float spart[(T / 64) * 256];
  const int tid = threadIdx.x;
  const int pt = blockIdx.x * T + tid;
  const float m = (float)cnt[pt];
  const float* pp = pts + (size_t)pt * 3;
  float* prow = partials + (size_t)blockIdx.x * 256;
  const float zx = pp[0], zy = pp[1], zz = pp[2];
  const float* sc0 = scshb;
  const float* sh0 = scshb + 128;
  v2h a0p[C02];
  #pragma unroll
  for (int c2 = 0; c2 < C02; ++c2) {
    float va = b0[2 * c2]     + zx * w0[6 * c2]     + zy * w0[6 * c2 + 1] + zz * w0[6 * c2 + 2];
    float vb = b0[2 * c2 + 1] + zx * w0[6 * c2 + 3] + zy * w0[6 * c2 + 4] + zz * w0[6 * c2 + 5];
    va = fmaxf(0.f, va * sc0[2 * c2] + sh0[2 * c2]);
    vb = fmaxf(0.f, vb * sc0[2 * c2 + 1] + sh0[2 * c2 + 1]);
    a0p[c2] = v2h{(_Float16)va, (_Float16)vb};
  }
  for (int CB = 0; CB < C1; CB += 32) {
    float arr[32];
    #pragma unroll
    for (int oo = 0; oo < 32; ++oo) {
      const int o = CB + oo;
      float s0 = 0.f, s1 = 0.f;
      #pragma unroll
      for (int c2 = 0; c2 < C02; c2 += 2) {
        s0 = fdot2(a0p[c2],     w1p[o * C02 + c2],     s0);
        s1 = fdot2(a0p[c2 + 1], w1p[o * C02 + c2 + 1], s1);
      }
      arr[oo] = b1[o] + (s0 + s1);
    }
    #pragma unroll
    for (int j = 0; j < 16; ++j)
      x1h2[(size_t)(CB / 2 + j) * 65536 + pt] = __floats2half2_rn(arr[2 * j], arr[2 * j + 1]);
    do_stats_w<32, 32, T>(arr, m, tid, spart, prow, 2 * CB);
  }
}

// ---------------------------------------------------------------- pass2: BN1+relu+L2 on distinct points
template<int C1, int C2, int T>
__global__ __launch_bounds__(T) void pass2_kernel(
    const __half2* __restrict__ x1h2, const int* __restrict__ cnt,
    const v2h* __restrict__ w2p, const float* __restrict__ b2,
    const float* __restrict__ scshb, float* __restrict__ partials,
    __half2* __restrict__ x2h2) {
  constexpr int C12 = C1 / 2;
  constexpr int CP = C2 / 2;
  constexpr int RSv = C12 + 1;                   // odd dword stride -> conflict-free
  __shared__ v2h arowv[T * RSv];
  __shared__ float spart[(T / 64) * 256];
  const int tid = threadIdx.x;
  const int pt = blockIdx.x * T + tid;
  const float m = (float)cnt[pt];
  float* prow = partials + (size_t)blockIdx.x * 256;
  const float* sc1 = scshb + 256;
  const float* sh1 = scshb + 384;
  for (int o2 = 0; o2 < C12; ++o2) {
    const float2 f = __half22float2(x1h2[(size_t)o2 * 65536 + pt]);
    const float xa = fmaxf(0.f, f.x * sc1[2 * o2] + sh1[2 * o2]);
    const float xb = fmaxf(0.f, f.y * sc1[2 * o2 + 1] + sh1[2 * o2 + 1]);
    arowv[tid * RSv + o2] = v2h{(_Float16)xa, (_Float16)xb};
  }
  for (int CB = 0; CB < C2; CB += 32) {
    float acc[32];
    #pragma unroll
    for (int j = 0; j < 32; ++j) acc[j] = b2[CB + j];
    for (int c2 = 0; c2 < C12; ++c2) {
      const v2h az = arowv[tid * RSv + c2];
      const v2h* wrow = w2p + c2 * C2 + CB;
      #pragma unroll
      for (int j = 0; j < 32; ++j) acc[j] = fdot2(az, wrow[j], acc[j]);
    }
    #pragma unroll
    for (int j = 0; j < 16; ++j)
      x2h2[(size_t)pt * CP + CB / 2 + j] = __floats2half2_rn(acc[2 * j], acc[2 * j + 1]);
    do_stats_w<32, 32, T>(acc, m, tid, spart, prow, 2 * CB);
  }
}

// ---------------------------------------------------------------- pool: gather-max + BN2 + relu
template<int K_, int C2, int BOFF>
__global__ __launch_bounds__(256) void pool_kernel(const __half2* __restrict__ x2h2,
                                                   const int* __restrict__ knn_,
                                                   const float* __restrict__ scshb,
                                                   float* __restrict__ out) {
  constexpr int CP = C2 / 2;
  const int g = blockIdx.x * 256 + threadIdx.x;  // < 8192 * CP
  const int cp = g % CP;
  const int s = g / CP;
  const int b = s >> 10;
  const int* kn = knn_ + s * 64;
  float mx0 = -1e30f, mx1 = -1e30f, mn0 = 1e30f, mn1 = 1e30f;
  for (int k = 0; k < K_; ++k) {
    const int idx = kn[k];
    const float2 f = __half22float2(x2h2[(size_t)(b * 8192 + idx) * CP + cp]);
    mx0 = fmaxf(mx0, f.x); mn0 = fminf(mn0, f.x);
    mx1 = fmaxf(mx1, f.y); mn1 = fminf(mn1, f.y);
  }
  const float sca = scshb[512 + 2 * cp], scb = scshb[512 + 2 * cp + 1];
  const float sha = scshb[640 + 2 * cp], shb = scshb[640 + 2 * cp + 1];
  float2 r;
  r.x = fmaxf(0.f, fmaf(sca, (sca >= 0.f) ? mx0 : mn0, sha));
  r.y = fmaxf(0.f, fmaf(scb, (scb >= 0.f) ? mx1 : mn1, shb));
  *(float2*)&out[(size_t)s * 320 + BOFF + 2 * cp] = r;
}

// ---------------------------------------------------------------- host side
template<int K_, int C0, int C1, int C2, int BOFF>
static void run_branch(const float* pts, const int* knn_, const int* cntb,
                       const float* const* W_, const float* const* B_,
                       const float* const* G_, const float* const* BE_,
                       float* scshb, float* partials, float* partials2,
                       const v2h* w1pb, const v2h* w2pb,
                       __half2* x1h2, __half2* x2h2, float* out, hipStream_t stream) {
  constexpr int T = 128;
  constexpr int NB = 65536 / T;                  // 512
  const float NEf = (float)(8 * 1024 * K_);
  pass1_kernel<C0, C1, T><<<NB, T, 0, stream>>>(
      pts, cntb, W_[0], B_[0], w1pb, B_[1], scshb, partials, x1h2);
  reduce_rows_kernel<<<32, 256, 0, stream>>>(partials, NB, partials2);
  finalize_kernel<<<1, 256, 0, stream>>>(partials2, 32, G_[1], BE_[1], NEf,
                                         scshb + 256, scshb + 384, C1);
  pass2_kernel<C1, C2, T><<<NB, T, 0, stream>>>(
      x1h2, cntb, w2pb, B_[2], scshb, partials, x2h2);
  reduce_rows_kernel<<<32, 256, 0, stream>>>(partials, NB, partials2);
  finalize_kernel<<<1, 256, 0, stream>>>(partials2, 32, G_[2], BE_[2], NEf,
                                         scshb + 512, scshb + 640, C2);
  pool_kernel<K_, C2, BOFF><<<8192 * (C2 / 2) / 256, 256, 0, stream>>>(
      x2h2, knn_, scshb, out);
}

extern "C" void kernel_launch(void* const* d_in, const int* in_sizes, int n_in,
                              void* d_out, int out_size, void* d_ws, size_t ws_size,
                              hipStream_t stream) {
  (void)in_sizes; (void)n_in; (void)out_size; (void)ws_size;
  const float* pts = (const float*)d_in[0];
  const float* W_[9]; const float* B_[9]; const float* G_[9]; const float* BE_[9];
  for (int m = 0; m < 9; ++m) {
    W_[m]  = (const float*)d_in[1 + m * 4 + 0];
    B_[m]  = (const float*)d_in[1 + m * 4 + 1];
    G_[m]  = (const float*)d_in[1 + m * 4 + 2];
    BE_[m] = (const float*)d_in[1 + m * 4 + 3];
  }
  char* ws = (char*)d_ws;
  float4*  cent     = (float4*)ws;                          // @0,        131072 B
  int*     knn_     = (int*)(ws + 131072);                  // 2 MB
  float*   partials = (float*)(ws + 2228224);               // 4 MB (also mpart)
  float*   scsh     = (float*)(ws + 6422528);               // 12 KB
  v2h*     w1h2     = (v2h*)(ws + 6434816);                 // 22528 B
  v2h*     w2h2     = (v2h*)(ws + 6457344);                 // 45056 B
  float*   partials2= (float*)(ws + 6502400);               // 32 KB
  int*     cnt      = (int*)(ws + 6535168);                 // 786432 B (3 x 65536)
  __half2* x1h2     = (__half2*)(ws + 7321600);             // 12582912 B (48 x 65536 x 4)
  __half2* x2h2     = (__half2*)(ws + 19904512);            // 16777216 B (65536 x 64 x 4)
  float*   out      = (float*)d_out;

  zero_kernel<<<768, 256, 0, stream>>>(cnt, 196608);
  fps_kernel<<<8, 512, 0, stream>>>(pts, cent);
  knn_kernel<<<2048, 256, 0, stream>>>(pts, cent, knn_, cnt, partials);
  finalize0_kernel<<<1, 256, 0, stream>>>(partials,
      W_[0], B_[0], G_[0], BE_[0], W_[3], B_[3], G_[3], BE_[3],
      W_[6], B_[6], G_[6], BE_[6], scsh);
  pack_kernel<<<66, 256, 0, stream>>>(W_[1], W_[4], W_[7], W_[2], W_[5], W_[8], w1h2, w2h2);

  run_branch<16, 32, 32, 64, 0>(pts, knn_, cnt, W_ + 0, B_ + 0, G_ + 0, BE_ + 0,
      scsh, partials, partials2, w1h2, w2h2, x1h2, x2h2, out, stream);
  run_branch<32, 64, 64, 128, 64>(pts, knn_, cnt + 65536, W_ + 3, B_ + 3, G_ + 3, BE_ + 3,
      scsh + 768, partials, partials2, w1h2 + 512, w2h2 + 1024, x1h2, x2h2, out, stream);
  run_branch<64, 64, 96, 128, 192>(pts, knn_, cnt + 131072, W_ + 6, B_ + 6, G_ + 6, BE_ + 6,
      scsh + 1536, partials, partials2, w1h2 + 2560, w2h2 + 5120, x1h2, x2h2, out, stream);
}

// Round 17
// 1731.492 us; speedup vs baseline: 1.4084x; 1.0501x over previous
//
#include <hip/hip_runtime.h>
#include <hip/hip_fp16.h>

#define DEVFN __device__ __forceinline__

typedef _Float16 v2h __attribute__((ext_vector_type(2)));

DEVFN float fdot2(v2h a, v2h b, float c) {
#if __has_builtin(__builtin_amdgcn_fdot2)
  return __builtin_amdgcn_fdot2(a, b, c, false);
#else
  return c + (float)a[0] * (float)b[0] + (float)a[1] * (float)b[1];
#endif
}

// ---------------------------------------------------------------- utilities
struct OpSum { DEVFN float operator()(float a, float b) const { return a + b; } };

template<int CH, int D, typename OP, int NV>
DEVFN void halve(float (&v)[NV], int lane, int& base) {
  if constexpr (D >= 1) {
    OP op;
    if constexpr (CH > 1) {
      constexpr int H = CH / 2;
      #pragma unroll
      for (int i = 0; i < H; ++i) {
        float send = (lane & D) ? v[i] : v[H + i];
        float r = __shfl_xor(send, D);
        float keep = (lane & D) ? v[H + i] : v[i];
        v[i] = op(keep, r);
      }
      if (lane & D) base += H;
      halve<H, (D >> 1), OP, NV>(v, lane, base);
    } else {
      v[0] = op(v[0], __shfl_xor(v[0], D));
      halve<CH, (D >> 1), OP, NV>(v, lane, base);
    }
  }
}

// Multiplicity-weighted sum + sumsq of a[0..CC) across T threads.
// prow row width is 768 floats.
template<int CC, int NA, int T>
DEVFN void do_stats_w(const float (&a)[NA], float m, int tid, float* spart,
                      float* prow, int statoff) {
  float v[2 * CC];
  #pragma unroll
  for (int j = 0; j < CC; ++j) { float x = a[j]; v[2 * j] = m * x; v[2 * j + 1] = m * x * x; }
  int lane = tid & 63, base = 0;
  halve<2 * CC, 32, OpSum, 2 * CC>(v, lane, base);
  int wv = tid >> 6;
  spart[wv * 256 + base] = v[0];
  __syncthreads();
  constexpr int NW = T / 64;
  if (tid < 2 * CC) {
    float s2 = 0.f;
    #pragma unroll
    for (int w = 0; w < NW; ++w) s2 += spart[w * 256 + tid];
    prow[statoff + tid] = s2;
  }
  __syncthreads();
}

// ---------------------------------------------------------------- FPS (structural floor)
__global__ __launch_bounds__(512) void fps_kernel(const float* __restrict__ pts,
                                                  float4* __restrict__ cent) {
  const int b = blockIdx.x, t = threadIdx.x;
  const int wv = t >> 6;
  __shared__ unsigned long long sk2[2][8];
  __shared__ float4 sc4[2][8];
  __shared__ float4 scent[1024];
  const float* p = pts + (size_t)b * 8192 * 3;
  float px[16], py[16], pz[16], dd[16];
  #pragma unroll
  for (int j = 0; j < 16; ++j) {
    const int i = t + j * 512;
    px[j] = p[i * 3]; py[j] = p[i * 3 + 1]; pz[j] = p[i * 3 + 2];
    dd[j] = 1e10f;
  }
  float cx = p[0], cy = p[1], cz = p[2];
  for (int it = 0; it < 1024; ++it) {
    if (t == 0) scent[it] = make_float4(cx, cy, cz, 0.f);
    const int par = it & 1;
    float bd = -1.f, bx = 0.f, by = 0.f, bz = 0.f; int bi = 0;
    #pragma unroll
    for (int j = 0; j < 16; ++j) {
      const float dx = px[j] - cx, dy = py[j] - cy, dz = pz[j] - cz;
      float d = fminf(dd[j], dx * dx + dy * dy + dz * dz);
      dd[j] = d;
      if (d > bd) { bd = d; bi = t + j * 512; bx = px[j]; by = py[j]; bz = pz[j]; }
    }
    float wmax = bd;
    #pragma unroll
    for (int m = 32; m >= 1; m >>= 1) wmax = fmaxf(wmax, __shfl_xor(wmax, m));
    const unsigned long long am = __ballot(bd == wmax);
    bool iswin;
    if (__popcll(am) == 1) {
      iswin = (bd == wmax);
    } else {
      int cand = (bd == wmax) ? bi : 0x7FFFFFFF;
      #pragma unroll
      for (int m = 32; m >= 1; m >>= 1) cand = min(cand, __shfl_xor(cand, m));
      iswin = (bd == wmax) && (bi == cand);
    }
    if (iswin) {
      sk2[par][wv] = ((unsigned long long)__float_as_uint(bd) << 32)
                     | (0xFFFFFFFFu - (unsigned)bi);
      sc4[par][wv] = make_float4(bx, by, bz, 0.f);
    }
    __syncthreads();
    unsigned long long gk = sk2[par][0];
    float4 c4 = sc4[par][0];
    #pragma unroll
    for (int w = 1; w < 8; ++w) {
      const unsigned long long k2 = sk2[par][w];
      const float4 cc = sc4[par][w];
      if (k2 > gk) { gk = k2; c4 = cc; }
    }
    cx = c4.x; cy = c4.y; cz = c4.z;
  }
  __syncthreads();
  #pragma unroll
  for (int i = t; i < 1024; i += 512) cent[(size_t)b * 1024 + i] = scent[i];
}

// ---------------------------------------------------------------- kNN + fused hist + fused moments
__global__ __launch_bounds__(256) void knn_kernel(const float* __restrict__ pts,
                                                  const float4* __restrict__ cent,
                                                  int* __restrict__ knn,
                                                  int* __restrict__ cnt,
                                                  float* __restrict__ mpart) {
  __shared__ float smom[4][27];
  const int tid = threadIdx.x;
  const int wv = tid >> 6;
  const int wid = blockIdx.x * 4 + wv;
  const int lane = tid & 63;
  const int b = wid >> 10;
  const float4 q = cent[wid];
  const float q2 = q.x * q.x + q.y * q.y + q.z * q.z;
  const float* p = pts + (size_t)b * 8192 * 3;
  unsigned long long R = ~0ull;
  for (int c0 = 0; c0 < 8192; c0 += 64) {
    const int i = c0 + lane;
    const float x = p[i * 3], y = p[i * 3 + 1], z = p[i * 3 + 2];
    const float p2 = x * x + y * y + z * z;
    const float dot = q.x * x + q.y * y + q.z * z;
    float d2 = q2 - 2.f * dot + p2;
    d2 = fmaxf(d2, 0.f);
    unsigned u = __float_as_uint(d2);
    u = (u & 0x80000000u) ? ~u : (u | 0x80000000u);
    const unsigned long long key = ((unsigned long long)u << 32) | (unsigned)i;
    const unsigned long long rmax = __shfl(R, 63);
    unsigned long long mask = __ballot(key < rmax);
    while (mask) {
      const int src = __ffsll(mask) - 1;
      mask &= mask - 1;
      const unsigned long long nk = __shfl(key, src);
      const int pos = __popcll(__ballot(R < nk));
      if (pos < 64) {
        const unsigned long long Rm1 = __shfl_up(R, 1);
        R = (lane < pos) ? R : (lane == pos ? nk : Rm1);
      }
    }
  }
  const int nidx = (int)(R & 0xffffffffu);
  knn[wid * 64 + lane] = nidx;

  const int gidx = b * 8192 + nidx;
  atomicAdd(&cnt[131072 + gidx], 1);
  if (lane < 32) atomicAdd(&cnt[65536 + gidx], 1);
  if (lane < 16) atomicAdd(&cnt[gidx], 1);

  const float* pp = pts + (size_t)gidx * 3;
  const float x = pp[0], y = pp[1], z = pp[2];
  float g[9] = {x, y, z, x * x, x * y, x * z, y * y, y * z, z * z};
  #pragma unroll
  for (int m = 8; m >= 1; m >>= 1) {
    #pragma unroll
    for (int i = 0; i < 9; ++i) g[i] += __shfl_xor(g[i], m);
  }
  float h[9], tot[9];
  #pragma unroll
  for (int i = 0; i < 9; ++i) h[i] = g[i] + __shfl_xor(g[i], 16);
  #pragma unroll
  for (int i = 0; i < 9; ++i) tot[i] = h[i] + __shfl_xor(h[i], 32);
  if (lane == 0) {
    #pragma unroll
    for (int i = 0; i < 9; ++i) {
      smom[wv][i] = g[i]; smom[wv][9 + i] = h[i]; smom[wv][18 + i] = tot[i];
    }
  }
  __syncthreads();
  if (tid < 27) {
    mpart[blockIdx.x * 32 + tid] =
        smom[0][tid] + smom[1][tid] + smom[2][tid] + smom[3][tid];
  }
}

// ---------------------------------------------------------------- BN0 finalize (all 3 branches)
__global__ __launch_bounds__(256) void finalize0_kernel(const float* __restrict__ mpart,
    const float* __restrict__ w00, const float* __restrict__ b00,
    const float* __restrict__ g00, const float* __restrict__ be00,
    const float* __restrict__ w01, const float* __restrict__ b01,
    const float* __restrict__ g01, const float* __restrict__ be01,
    const float* __restrict__ w02, const float* __restrict__ b02,
    const float* __restrict__ g02, const float* __restrict__ be02,
    float* __restrict__ scsh) {
  __shared__ float fsum[8][32];
  __shared__ float mom[32];
  const int t = threadIdx.x;
  const int col = t & 31, chunk = t >> 5;
  float s = 0.f;
  for (int r = chunk * 256; r < chunk * 256 + 256; ++r) s += mpart[r * 32 + col];
  fsum[chunk][col] = s;
  __syncthreads();
  if (t < 32) {
    float s2 = 0.f;
    #pragma unroll
    for (int c = 0; c < 8; ++c) s2 += fsum[c][t];
    mom[t] = s2;
  }
  __syncthreads();
  int o; const float *w, *bb, *gg, *be; float E; int base, br;
  if (t < 32)       { br = 0; o = t;      w = w00; bb = b00; gg = g00; be = be00; E = 131072.f; base = 0; }
  else if (t < 96)  { br = 1; o = t - 32; w = w01; bb = b01; gg = g01; be = be01; E = 262144.f; base = 9; }
  else if (t < 160) { br = 2; o = t - 96; w = w02; bb = b02; gg = g02; be = be02; E = 524288.f; base = 18; }
  else return;
  const float Sx = mom[base], Sy = mom[base + 1], Sz = mom[base + 2];
  const float mxx = mom[base + 3], mxy = mom[base + 4], mxz = mom[base + 5];
  const float myy = mom[base + 6], myz = mom[base + 7], mzz = mom[base + 8];
  const float W0 = w[o * 3], W1 = w[o * 3 + 1], W2 = w[o * 3 + 2], bo = bb[o];
  const float wS = W0 * Sx + W1 * Sy + W2 * Sz;
  const float qf = W0 * W0 * mxx + 2.f * W0 * W1 * mxy + 2.f * W0 * W2 * mxz
                 + W1 * W1 * myy + 2.f * W1 * W2 * myz + W2 * W2 * mzz;
  const float mean = wS / E + bo;
  const float msq = (qf + 2.f * bo * wS) / E + bo * bo;
  const float var = msq - mean * mean;
  const float inv = 1.0f / sqrtf(var + 1e-5f);
  const float sc = gg[o] * inv;
  scsh[br * 768 + o] = sc;
  scsh[br * 768 + 128 + o] = be[o] - mean * sc;
}

// ---------------------------------------------------------------- pack w1/w2 as half2 pairs
__global__ __launch_bounds__(256) void pack_kernel(
    const float* __restrict__ w1a, const float* __restrict__ w1b, const float* __restrict__ w1c,
    const float* __restrict__ w2a, const float* __restrict__ w2b, const float* __restrict__ w2c,
    v2h* __restrict__ w1h2, v2h* __restrict__ w2h2) {
  const int i = blockIdx.x * 256 + threadIdx.x;
  if (i < 512) {                                   // b1 w1: C0=32, C1=32
    const int o = i >> 4, c2 = i & 15;
    w1h2[i] = v2h{(_Float16)w1a[o * 32 + 2 * c2], (_Float16)w1a[o * 32 + 2 * c2 + 1]};
  } else if (i < 2560) {                           // b2 w1: C0=64, C1=64
    const int j = i - 512, o = j >> 5, c2 = j & 31;
    w1h2[i] = v2h{(_Float16)w1b[o * 64 + 2 * c2], (_Float16)w1b[o * 64 + 2 * c2 + 1]};
  } else if (i < 5632) {                           // b3 w1: C0=64, C1=96
    const int j = i - 2560, o = j >> 5, c2 = j & 31;
    w1h2[i] = v2h{(_Float16)w1c[o * 64 + 2 * c2], (_Float16)w1c[o * 64 + 2 * c2 + 1]};
  } else if (i < 6656) {                           // b1 w2: C1=32, C2=64
    const int j = i - 5632, c2 = j >> 6, jj = j & 63;
    w2h2[j] = v2h{(_Float16)w2a[jj * 32 + 2 * c2], (_Float16)w2a[jj * 32 + 2 * c2 + 1]};
  } else if (i < 10752) {                          // b2 w2: C1=64, C2=128
    const int j = i - 6656, c2 = j >> 7, jj = j & 127;
    w2h2[1024 + j] = v2h{(_Float16)w2b[jj * 64 + 2 * c2], (_Float16)w2b[jj * 64 + 2 * c2 + 1]};
  } else if (i < 16896) {                          // b3 w2: C1=96, C2=128
    const int j = i - 10752, c2 = j >> 7, jj = j & 127;
    w2h2[5120 + j] = v2h{(_Float16)w2c[jj * 96 + 2 * c2], (_Float16)w2c[jj * 96 + 2 * c2 + 1]};
  }
}

// ---------------------------------------------------------------- zero (multiplicities)
__global__ __launch_bounds__(256) void zero_kernel(int* __restrict__ p, int n) {
  const int i = blockIdx.x * 256 + threadIdx.x;
  if (i < n) p[i] = 0;
}

// ---------------------------------------------------------------- reduce 512 partial rows -> 32 (width 768)
__global__ __launch_bounds__(256) void reduce_rows_kernel(const float* __restrict__ partials,
                                                          float* __restrict__ out32) {
  const int r0 = blockIdx.x;
  for (int j = threadIdx.x; j < 768; j += 256) {
    float s = 0.f;
    for (int r = r0 * 16; r < r0 * 16 + 16; ++r) s += partials[(size_t)r * 768 + j];
    out32[r0 * 768 + j] = s;
  }
}

// ---------------------------------------------------------------- BN1 finalize (all 3 branches)
// pass1 stat col layout: branch bases {0,64,192}; channel o: col = base + (o>>5)*64 + 2*(o&31).
__global__ __launch_bounds__(256) void finalizeA_kernel(const float* __restrict__ p2,
    const float* __restrict__ g1, const float* __restrict__ be1,
    const float* __restrict__ g2, const float* __restrict__ be2,
    const float* __restrict__ g3, const float* __restrict__ be3,
    float* __restrict__ scsh) {
  const int t = threadIdx.x;
  int br, o;
  if (t < 32)       { br = 0; o = t; }
  else if (t < 96)  { br = 1; o = t - 32; }
  else if (t < 192) { br = 2; o = t - 96; }
  else return;
  const int base = (br == 0) ? 0 : (br == 1) ? 64 : 192;
  const float E = (br == 0) ? 131072.f : (br == 1) ? 262144.f : 524288.f;
  const float* g  = (br == 0) ? g1 : (br == 1) ? g2 : g3;
  const float* be = (br == 0) ? be1 : (br == 1) ? be2 : be3;
  const int cs = base + ((o >> 5) << 6) + 2 * (o & 31);
  float sm = 0.f, sq = 0.f;
  for (int r = 0; r < 32; ++r) { sm += p2[r * 768 + cs]; sq += p2[r * 768 + cs + 1]; }
  const float mean = sm / E;
  const float var = sq / E - mean * mean;
  const float inv = 1.0f / sqrtf(var + 1e-5f);
  const float sc = g[o] * inv;
  scsh[br * 768 + 256 + o] = sc;
  scsh[br * 768 + 384 + o] = be[o] - mean * sc;
}

// ---------------------------------------------------------------- BN2 finalize (all 3 branches)
// pass2 stat col layout: branch bases {0,128,384}.
__global__ __launch_bounds__(512) void finalizeB_kernel(const float* __restrict__ p2,
    const float* __restrict__ g1, const float* __restrict__ be1,
    const float* __restrict__ g2, const float* __restrict__ be2,
    const float* __restrict__ g3, const float* __restrict__ be3,
    float* __restrict__ scsh) {
  const int t = threadIdx.x;
  int br, o;
  if (t < 64)       { br = 0; o = t; }
  else if (t < 192) { br = 1; o = t - 64; }
  else if (t < 320) { br = 2; o = t - 192; }
  else return;
  const int base = (br == 0) ? 0 : (br == 1) ? 128 : 384;
  const float E = (br == 0) ? 131072.f : (br == 1) ? 262144.f : 524288.f;
  const float* g  = (br == 0) ? g1 : (br == 1) ? g2 : g3;
  const float* be = (br == 0) ? be1 : (br == 1) ? be2 : be3;
  const int cs = base + ((o >> 5) << 6) + 2 * (o & 31);
  float sm = 0.f, sq = 0.f;
  for (int r = 0; r < 32; ++r) { sm += p2[r * 768 + cs]; sq += p2[r * 768 + cs + 1]; }
  const float mean = sm / E;
  const float var = sq / E - mean * mean;
  const float inv = 1.0f / sqrtf(var + 1e-5f);
  const float sc = g[o] * inv;
  scsh[br * 768 + 512 + o] = sc;
  scsh[br * 768 + 640 + o] = be[o] - mean * sc;
}

// ---------------------------------------------------------------- pass1 branch body
template<int C0, int C1, int T, int X1OFF, int SOFF>
DEVFN void p1_branch(int tid, int pt, float zx, float zy, float zz, float m,
                     const float* __restrict__ w0, const float* __restrict__ b0,
                     const v2h* __restrict__ w1p, const float* __restrict__ b1,
                     const float* __restrict__ scshb,
                     float* spart, float* prow, __half2* __restrict__ x1h2) {
  constexpr int C02 = C0 / 2;
  const float* sc0 = scshb;
  const float* sh0 = scshb + 128;
  v2h a0p[C02];
  #pragma unroll
  for (int c2 = 0; c2 < C02; ++c2) {
    float va = b0[2 * c2]     + zx * w0[6 * c2]     + zy * w0[6 * c2 + 1] + zz * w0[6 * c2 + 2];
    float vb = b0[2 * c2 + 1] + zx * w0[6 * c2 + 3] + zy * w0[6 * c2 + 4] + zz * w0[6 * c2 + 5];
    va = fmaxf(0.f, va * sc0[2 * c2] + sh0[2 * c2]);
    vb = fmaxf(0.f, vb * sc0[2 * c2 + 1] + sh0[2 * c2 + 1]);
    a0p[c2] = v2h{(_Float16)va, (_Float16)vb};
  }
  #pragma unroll
  for (int CB = 0; CB < C1; CB += 32) {
    float arr[32];
    #pragma unroll
    for (int oo = 0; oo < 32; ++oo) {
      const int o = CB + oo;
      float s0 = 0.f, s1 = 0.f;
      #pragma unroll
      for (int c2 = 0; c2 < C02; c2 += 2) {
        s0 = fdot2(a0p[c2],     w1p[o * C02 + c2],     s0);
        s1 = fdot2(a0p[c2 + 1], w1p[o * C02 + c2 + 1], s1);
      }
      arr[oo] = b1[o] + (s0 + s1);
    }
    #pragma unroll
    for (int j = 0; j < 16; ++j)
      x1h2[(size_t)(X1OFF + CB / 2 + j) * 65536 + pt] = __floats2half2_rn(arr[2 * j], arr[2 * j + 1]);
    do_stats_w<32, 32, T>(arr, m, tid, spart, prow, SOFF + (CB / 32) * 64);
  }
}

// ---------------------------------------------------------------- pass1all (3 branches)
template<int T>
__global__ __launch_bounds__(T) void pass1all_kernel(
    const float* __restrict__ pts, const int* __restrict__ cnt,
    const float* __restrict__ w0a, const float* __restrict__ b0a,
    const v2h* __restrict__ w1pa, const float* __restrict__ b1a,
    const float* __restrict__ w0b, const float* __restrict__ b0b,
    const v2h* __restrict__ w1pb, const float* __restrict__ b1b,
    const float* __restrict__ w0c, const float* __restrict__ b0c,
    const v2h* __restrict__ w1pc, const float* __restrict__ b1c,
    const float* __restrict__ scsh, float* __restrict__ partials,
    __half2* __restrict__ x1h2) {
  __shared__ float spart[(T / 64) * 256];
  const int tid = threadIdx.x;
  const int pt = blockIdx.x * T + tid;
  const float* pp = pts + (size_t)pt * 3;
  const float zx = pp[0], zy = pp[1], zz = pp[2];
  float* prow = partials + (size_t)blockIdx.x * 768;
  p1_branch<32, 32, T, 0, 0>(tid, pt, zx, zy, zz, (float)cnt[pt],
      w0a, b0a, w1pa, b1a, scsh, spart, prow, x1h2);
  p1_branch<64, 64, T, 16, 64>(tid, pt, zx, zy, zz, (float)cnt[65536 + pt],
      w0b, b0b, w1pb, b1b, scsh + 768, spart, prow, x1h2);
  p1_branch<64, 96, T, 48, 192>(tid, pt, zx, zy, zz, (float)cnt[131072 + pt],
      w0c, b0c, w1pc, b1c, scsh + 1536, spart, prow, x1h2);
}

// ---------------------------------------------------------------- pass2 branch body
template<int C1, int C2, int T, int X1OFF, int SOFF>
DEVFN void p2_branch(int tid, int pt, float m, const __half2* __restrict__ x1h2,
                     const v2h* __restrict__ w2p, const float* __restrict__ b2,
                     const float* __restrict__ scshb, v2h* arowv,
                     float* spart, float* prow, __half2* __restrict__ x2out) {
  constexpr int C12 = C1 / 2;
  constexpr int RSv = C12 + 1;
  constexpr int CP = C2 / 2;
  const float* sc1 = scshb + 256;
  const float* sh1 = scshb + 384;
  v2h* myrow = arowv + tid * RSv;
  for (int o2 = 0; o2 < C12; ++o2) {
    const float2 f = __half22float2(x1h2[(size_t)(X1OFF + o2) * 65536 + pt]);
    const float xa = fmaxf(0.f, f.x * sc1[2 * o2] + sh1[2 * o2]);
    const float xb = fmaxf(0.f, f.y * sc1[2 * o2 + 1] + sh1[2 * o2 + 1]);
    myrow[o2] = v2h{(_Float16)xa, (_Float16)xb};
  }
  #pragma unroll
  for (int CB = 0; CB < C2; CB += 32) {
    float acc[32];
    #pragma unroll
    for (int j = 0; j < 32; ++j) acc[j] = b2[CB + j];
    for (int c2 = 0; c2 < C12; ++c2) {
      const v2h az = myrow[c2];
      const v2h* wrow = w2p + c2 * C2 + CB;
      #pragma unroll
      for (int j = 0; j < 32; ++j) acc[j] = fdot2(az, wrow[j], acc[j]);
    }
    #pragma unroll
    for (int j = 0; j < 16; ++j)
      x2out[(size_t)pt * CP + CB / 2 + j] = __floats2half2_rn(acc[2 * j], acc[2 * j + 1]);
    do_stats_w<32, 32, T>(acc, m, tid, spart, prow, SOFF + (CB / 32) * 64);
  }
}

// ---------------------------------------------------------------- pass2all (3 branches)
template<int T>
__global__ __launch_bounds__(T) void pass2all_kernel(
    const __half2* __restrict__ x1h2, const int* __restrict__ cnt,
    const v2h* __restrict__ w2pa, const float* __restrict__ b2a,
    const v2h* __restrict__ w2pb, const float* __restrict__ b2b,
    const v2h* __restrict__ w2pc, const float* __restrict__ b2c,
    const float* __restrict__ scsh, float* __restrict__ partials,
    __half2* __restrict__ x2h2) {
  __shared__ v2h arowv[T * 49];
  __shared__ float spart[(T / 64) * 256];
  const int tid = threadIdx.x;
  const int pt = blockIdx.x * T + tid;
  float* prow = partials + (size_t)blockIdx.x * 768;
  p2_branch<32, 64, T, 0, 0>(tid, pt, (float)cnt[pt], x1h2,
      w2pa, b2a, scsh, arowv, spart, prow, x2h2);
  p2_branch<64, 128, T, 16, 128>(tid, pt, (float)cnt[65536 + pt], x1h2,
      w2pb, b2b, scsh + 768, arowv, spart, prow, x2h2 + (size_t)65536 * 32);
  p2_branch<96, 128, T, 48, 384>(tid, pt, (float)cnt[131072 + pt], x1h2,
      w2pc, b2c, scsh + 1536, arowv, spart, prow, x2h2 + (size_t)65536 * 96);
}

// ---------------------------------------------------------------- pool (all 3 branches)
__global__ __launch_bounds__(256) void poolall_kernel(const __half2* __restrict__ x2h2,
                                                      const int* __restrict__ knn_,
                                                      const float* __restrict__ scsh,
                                                      float* __restrict__ out) {
  const int gid = blockIdx.x * 256 + threadIdx.x;
  int K, CP, s, cp, boff;
  const __half2* xb; const float* scb;
  if (gid < 262144) {                       // b1: 8192 x 32 pairs
    K = 16; CP = 32; s = gid >> 5; cp = gid & 31;
    xb = x2h2; scb = scsh; boff = 0;
  } else if (gid < 786432) {                // b2: 8192 x 64 pairs
    const int l = gid - 262144;
    K = 32; CP = 64; s = l >> 6; cp = l & 63;
    xb = x2h2 + (size_t)65536 * 32; scb = scsh + 768; boff = 64;
  } else {                                  // b3: 8192 x 64 pairs
    const int l = gid - 786432;
    K = 64; CP = 64; s = l >> 6; cp = l & 63;
    xb = x2h2 + (size_t)65536 * 96; scb = scsh + 1536; boff = 192;
  }
  const int b = s >> 10;
  const int* kn = knn_ + s * 64;
  float mx0 = -1e30f, mx1 = -1e30f, mn0 = 1e30f, mn1 = 1e30f;
  #pragma unroll 8
  for (int k = 0; k < K; ++k) {
    const int idx = kn[k];
    const float2 f = __half22float2(xb[(size_t)(b * 8192 + idx) * CP + cp]);
    mx0 = fmaxf(mx0, f.x); mn0 = fminf(mn0, f.x);
    mx1 = fmaxf(mx1, f.y); mn1 = fminf(mn1, f.y);
  }
  const float sca = scb[512 + 2 * cp], sccb = scb[512 + 2 * cp + 1];
  const float sha = scb[640 + 2 * cp], shb = scb[640 + 2 * cp + 1];
  float2 r;
  r.x = fmaxf(0.f, fmaf(sca, (sca >= 0.f) ? mx0 : mn0, sha));
  r.y = fmaxf(0.f, fmaf(sccb, (sccb >= 0.f) ? mx1 : mn1, shb));
  *(float2*)&out[(size_t)s * 320 + boff + 2 * cp] = r;
}

// ---------------------------------------------------------------- host side
extern "C" void kernel_launch(void* const* d_in, const int* in_sizes, int n_in,
                              void* d_out, int out_size, void* d_ws, size_t ws_size,
                              hipStream_t stream) {
  (void)in_sizes; (void)n_in; (void)out_size; (void)ws_size;
  const float* pts = (const float*)d_in[0];
  const float* W_[9]; const float* B_[9]; const float* G_[9]; const float* BE_[9];
  for (int m = 0; m < 9; ++m) {
    W_[m]  = (const float*)d_in[1 + m * 4 + 0];
    B_[m]  = (const float*)d_in[1 + m * 4 + 1];
    G_[m]  = (const float*)d_in[1 + m * 4 + 2];
    BE_[m] = (const float*)d_in[1 + m * 4 + 3];
  }
  char* ws = (char*)d_ws;
  float4*  cent     = (float4*)ws;                          // @0,        131072 B
  int*     knn_     = (int*)(ws + 131072);                  // 2 MB
  float*   partials = (float*)(ws + 2228224);               // 512 x 768 x 4 = 1.5MB (also mpart 256KB)
  float*   scsh     = (float*)(ws + 6422528);               // 12 KB
  v2h*     w1h2     = (v2h*)(ws + 6434816);                 // 22528 B
  v2h*     w2h2     = (v2h*)(ws + 6457344);                 // 45056 B
  float*   partials2= (float*)(ws + 6502400);               // 32 x 768 x 4 = 96 KB
  int*     cnt      = (int*)(ws + 6600704);                 // 786432 B
  __half2* x1h2     = (__half2*)(ws + 7387136);             // 96 x 65536 x 4 = 24 MB
  __half2* x2h2     = (__half2*)(ws + 32552960);            // 160 x 65536 x 4 = 40 MB
  float*   out      = (float*)d_out;

  zero_kernel<<<768, 256, 0, stream>>>(cnt, 196608);
  fps_kernel<<<8, 512, 0, stream>>>(pts, cent);
  knn_kernel<<<2048, 256, 0, stream>>>(pts, cent, knn_, cnt, partials);
  finalize0_kernel<<<1, 256, 0, stream>>>(partials,
      W_[0], B_[0], G_[0], BE_[0], W_[3], B_[3], G_[3], BE_[3],
      W_[6], B_[6], G_[6], BE_[6], scsh);
  pack_kernel<<<66, 256, 0, stream>>>(W_[1], W_[4], W_[7], W_[2], W_[5], W_[8], w1h2, w2h2);

  constexpr int T = 128;
  pass1all_kernel<T><<<65536 / T, T, 0, stream>>>(
      pts, cnt, W_[0], B_[0], w1h2, B_[1], W_[3], B_[3], w1h2 + 512, B_[4],
      W_[6], B_[6], w1h2 + 2560, B_[7], scsh, partials, x1h2);
  reduce_rows_kernel<<<32, 256, 0, stream>>>(partials, partials2);
  finalizeA_kernel<<<1, 256, 0, stream>>>(partials2, G_[1], BE_[1], G_[4], BE_[4],
                                          G_[7], BE_[7], scsh);
  pass2all_kernel<T><<<65536 / T, T, 0, stream>>>(
      x1h2, cnt, w2h2, B_[2], w2h2 + 1024, B_[5], w2h2 + 5120, B_[8],
      scsh, partials, x2h2);
  reduce_rows_kernel<<<32, 256, 0, stream>>>(partials, partials2);
  finalizeB_kernel<<<1, 512, 0, stream>>>(partials2, G_[2], BE_[2], G_[5], BE_[5],
                                          G_[8], BE_[8], scsh);
  poolall_kernel<<<5120, 256, 0, stream>>>(x2h2, knn_, scsh, out);
}

// Round 18
// 1727.803 us; speedup vs baseline: 1.4114x; 1.0021x over previous
//
#include <hip/hip_runtime.h>
#include <hip/hip_fp16.h>

#define DEVFN __device__ __forceinline__

typedef _Float16 v2h __attribute__((ext_vector_type(2)));

DEVFN float fdot2(v2h a, v2h b, float c) {
#if __has_builtin(__builtin_amdgcn_fdot2)
  return __builtin_amdgcn_fdot2(a, b, c, false);
#else
  return c + (float)a[0] * (float)b[0] + (float)a[1] * (float)b[1];
#endif
}

// ---------------------------------------------------------------- utilities
struct OpSum { DEVFN float operator()(float a, float b) const { return a + b; } };

template<int CH, int D, typename OP, int NV>
DEVFN void halve(float (&v)[NV], int lane, int& base) {
  if constexpr (D >= 1) {
    OP op;
    if constexpr (CH > 1) {
      constexpr int H = CH / 2;
      #pragma unroll
      for (int i = 0; i < H; ++i) {
        float send = (lane & D) ? v[i] : v[H + i];
        float r = __shfl_xor(send, D);
        float keep = (lane & D) ? v[H + i] : v[i];
        v[i] = op(keep, r);
      }
      if (lane & D) base += H;
      halve<H, (D >> 1), OP, NV>(v, lane, base);
    } else {
      v[0] = op(v[0], __shfl_xor(v[0], D));
      halve<CH, (D >> 1), OP, NV>(v, lane, base);
    }
  }
}

// Multiplicity-weighted sum + sumsq of a[0..CC) across T threads.
// prow row width is 768 floats.
template<int CC, int NA, int T>
DEVFN void do_stats_w(const float (&a)[NA], float m, int tid, float* spart,
                      float* prow, int statoff) {
  float v[2 * CC];
  #pragma unroll
  for (int j = 0; j < CC; ++j) { float x = a[j]; v[2 * j] = m * x; v[2 * j + 1] = m * x * x; }
  int lane = tid & 63, base = 0;
  halve<2 * CC, 32, OpSum, 2 * CC>(v, lane, base);
  int wv = tid >> 6;
  spart[wv * 256 + base] = v[0];
  __syncthreads();
  constexpr int NW = T / 64;
  if (tid < 2 * CC) {
    float s2 = 0.f;
    #pragma unroll
    for (int w = 0; w < NW; ++w) s2 += spart[w * 256 + tid];
    prow[statoff + tid] = s2;
  }
  __syncthreads();
}

// ---------------------------------------------------------------- FPS (structural floor)
__global__ __launch_bounds__(512) void fps_kernel(const float* __restrict__ pts,
                                                  float4* __restrict__ cent) {
  const int b = blockIdx.x, t = threadIdx.x;
  const int wv = t >> 6;
  __shared__ unsigned long long sk2[2][8];
  __shared__ float4 sc4[2][8];
  __shared__ float4 scent[1024];
  const float* p = pts + (size_t)b * 8192 * 3;
  float px[16], py[16], pz[16], dd[16];
  #pragma unroll
  for (int j = 0; j < 16; ++j) {
    const int i = t + j * 512;
    px[j] = p[i * 3]; py[j] = p[i * 3 + 1]; pz[j] = p[i * 3 + 2];
    dd[j] = 1e10f;
  }
  float cx = p[0], cy = p[1], cz = p[2];
  for (int it = 0; it < 1024; ++it) {
    if (t == 0) scent[it] = make_float4(cx, cy, cz, 0.f);
    const int par = it & 1;
    float bd = -1.f, bx = 0.f, by = 0.f, bz = 0.f; int bi = 0;
    #pragma unroll
    for (int j = 0; j < 16; ++j) {
      const float dx = px[j] - cx, dy = py[j] - cy, dz = pz[j] - cz;
      float d = fminf(dd[j], dx * dx + dy * dy + dz * dz);
      dd[j] = d;
      if (d > bd) { bd = d; bi = t + j * 512; bx = px[j]; by = py[j]; bz = pz[j]; }
    }
    float wmax = bd;
    #pragma unroll
    for (int m = 32; m >= 1; m >>= 1) wmax = fmaxf(wmax, __shfl_xor(wmax, m));
    const unsigned long long am = __ballot(bd == wmax);
    bool iswin;
    if (__popcll(am) == 1) {
      iswin = (bd == wmax);
    } else {
      int cand = (bd == wmax) ? bi : 0x7FFFFFFF;
      #pragma unroll
      for (int m = 32; m >= 1; m >>= 1) cand = min(cand, __shfl_xor(cand, m));
      iswin = (bd == wmax) && (bi == cand);
    }
    if (iswin) {
      sk2[par][wv] = ((unsigned long long)__float_as_uint(bd) << 32)
                     | (0xFFFFFFFFu - (unsigned)bi);
      sc4[par][wv] = make_float4(bx, by, bz, 0.f);
    }
    __syncthreads();
    unsigned long long gk = sk2[par][0];
    float4 c4 = sc4[par][0];
    #pragma unroll
    for (int w = 1; w < 8; ++w) {
      const unsigned long long k2 = sk2[par][w];
      const float4 cc = sc4[par][w];
      if (k2 > gk) { gk = k2; c4 = cc; }
    }
    cx = c4.x; cy = c4.y; cz = c4.z;
  }
  __syncthreads();
  #pragma unroll
  for (int i = t; i < 1024; i += 512) cent[(size_t)b * 1024 + i] = scent[i];
}

// ---------------------------------------------------------------- prep: zero cnt + pts4 + weight pack
__global__ __launch_bounds__(256) void prep_kernel(const float* __restrict__ pts,
    int* __restrict__ cnt, float4* __restrict__ pts4,
    const float* __restrict__ w1a, const float* __restrict__ w1b, const float* __restrict__ w1c,
    const float* __restrict__ w2a, const float* __restrict__ w2b, const float* __restrict__ w2c,
    v2h* __restrict__ w1h2, v2h* __restrict__ w2h2) {
  const int i = blockIdx.x * 256 + threadIdx.x;
  if (i < 196608) cnt[i] = 0;
  if (i < 65536)
    pts4[i] = make_float4(pts[i * 3], pts[i * 3 + 1], pts[i * 3 + 2], 0.f);
  if (i < 512) {                                   // b1 w1: C0=32, C1=32
    const int o = i >> 4, c2 = i & 15;
    w1h2[i] = v2h{(_Float16)w1a[o * 32 + 2 * c2], (_Float16)w1a[o * 32 + 2 * c2 + 1]};
  } else if (i < 2560) {                           // b2 w1: C0=64, C1=64
    const int j = i - 512, o = j >> 5, c2 = j & 31;
    w1h2[i] = v2h{(_Float16)w1b[o * 64 + 2 * c2], (_Float16)w1b[o * 64 + 2 * c2 + 1]};
  } else if (i < 5632) {                           // b3 w1: C0=64, C1=96
    const int j = i - 2560, o = j >> 5, c2 = j & 31;
    w1h2[i] = v2h{(_Float16)w1c[o * 64 + 2 * c2], (_Float16)w1c[o * 64 + 2 * c2 + 1]};
  } else if (i < 6656) {                           // b1 w2: C1=32, C2=64
    const int j = i - 5632, c2 = j >> 6, jj = j & 63;
    w2h2[j] = v2h{(_Float16)w2a[jj * 32 + 2 * c2], (_Float16)w2a[jj * 32 + 2 * c2 + 1]};
  } else if (i < 10752) {                          // b2 w2: C1=64, C2=128
    const int j = i - 6656, c2 = j >> 7, jj = j & 127;
    w2h2[1024 + j] = v2h{(_Float16)w2b[jj * 64 + 2 * c2], (_Float16)w2b[jj * 64 + 2 * c2 + 1]};
  } else if (i < 16896) {                          // b3 w2: C1=96, C2=128
    const int j = i - 10752, c2 = j >> 7, jj = j & 127;
    w2h2[5120 + j] = v2h{(_Float16)w2c[jj * 96 + 2 * c2], (_Float16)w2c[jj * 96 + 2 * c2 + 1]};
  }
}

// ---------------------------------------------------------------- kNN + fused hist + fused moments
__global__ __launch_bounds__(256) void knn_kernel(const float4* __restrict__ pts4,
                                                  const float* __restrict__ pts,
                                                  const float4* __restrict__ cent,
                                                  int* __restrict__ knn,
                                                  int* __restrict__ cnt,
                                                  float* __restrict__ mpart) {
  __shared__ float smom[4][27];
  const int tid = threadIdx.x;
  const int wv = tid >> 6;
  const int wid = blockIdx.x * 4 + wv;
  const int lane = tid & 63;
  const int b = wid >> 10;
  const float4 q = cent[wid];
  const float q2 = q.x * q.x + q.y * q.y + q.z * q.z;
  const float4* p4 = pts4 + (size_t)b * 8192;
  unsigned long long R = ~0ull;
  for (int c0 = 0; c0 < 8192; c0 += 64) {
    const int i = c0 + lane;
    const float4 v = p4[i];
    const float x = v.x, y = v.y, z = v.z;
    const float p2 = x * x + y * y + z * z;
    const float dot = q.x * x + q.y * y + q.z * z;
    float d2 = q2 - 2.f * dot + p2;
    d2 = fmaxf(d2, 0.f);
    unsigned u = __float_as_uint(d2);
    u = (u & 0x80000000u) ? ~u : (u | 0x80000000u);
    const unsigned long long key = ((unsigned long long)u << 32) | (unsigned)i;
    const unsigned long long rmax = __shfl(R, 63);
    unsigned long long mask = __ballot(key < rmax);
    while (mask) {
      const int src = __ffsll(mask) - 1;
      mask &= mask - 1;
      const unsigned long long nk = __shfl(key, src);
      const int pos = __popcll(__ballot(R < nk));
      if (pos < 64) {
        const unsigned long long Rm1 = __shfl_up(R, 1);
        R = (lane < pos) ? R : (lane == pos ? nk : Rm1);
      }
    }
  }
  const int nidx = (int)(R & 0xffffffffu);
  knn[wid * 64 + lane] = nidx;

  const int gidx = b * 8192 + nidx;
  atomicAdd(&cnt[131072 + gidx], 1);
  if (lane < 32) atomicAdd(&cnt[65536 + gidx], 1);
  if (lane < 16) atomicAdd(&cnt[gidx], 1);

  const float* pp = pts + (size_t)gidx * 3;
  const float x = pp[0], y = pp[1], z = pp[2];
  float g[9] = {x, y, z, x * x, x * y, x * z, y * y, y * z, z * z};
  #pragma unroll
  for (int m = 8; m >= 1; m >>= 1) {
    #pragma unroll
    for (int i = 0; i < 9; ++i) g[i] += __shfl_xor(g[i], m);
  }
  float h[9], tot[9];
  #pragma unroll
  for (int i = 0; i < 9; ++i) h[i] = g[i] + __shfl_xor(g[i], 16);
  #pragma unroll
  for (int i = 0; i < 9; ++i) tot[i] = h[i] + __shfl_xor(h[i], 32);
  if (lane == 0) {
    #pragma unroll
    for (int i = 0; i < 9; ++i) {
      smom[wv][i] = g[i]; smom[wv][9 + i] = h[i]; smom[wv][18 + i] = tot[i];
    }
  }
  __syncthreads();
  if (tid < 27) {
    mpart[blockIdx.x * 32 + tid] =
        smom[0][tid] + smom[1][tid] + smom[2][tid] + smom[3][tid];
  }
}

// ---------------------------------------------------------------- BN0 finalize (all 3 branches)
__global__ __launch_bounds__(256) void finalize0_kernel(const float* __restrict__ mpart,
    const float* __restrict__ w00, const float* __restrict__ b00,
    const float* __restrict__ g00, const float* __restrict__ be00,
    const float* __restrict__ w01, const float* __restrict__ b01,
    const float* __restrict__ g01, const float* __restrict__ be01,
    const float* __restrict__ w02, const float* __restrict__ b02,
    const float* __restrict__ g02, const float* __restrict__ be02,
    float* __restrict__ scsh) {
  __shared__ float fsum[8][32];
  __shared__ float mom[32];
  const int t = threadIdx.x;
  const int col = t & 31, chunk = t >> 5;
  float s = 0.f;
  for (int r = chunk * 256; r < chunk * 256 + 256; ++r) s += mpart[r * 32 + col];
  fsum[chunk][col] = s;
  __syncthreads();
  if (t < 32) {
    float s2 = 0.f;
    #pragma unroll
    for (int c = 0; c < 8; ++c) s2 += fsum[c][t];
    mom[t] = s2;
  }
  __syncthreads();
  int o; const float *w, *bb, *gg, *be; float E; int base, br;
  if (t < 32)       { br = 0; o = t;      w = w00; bb = b00; gg = g00; be = be00; E = 131072.f; base = 0; }
  else if (t < 96)  { br = 1; o = t - 32; w = w01; bb = b01; gg = g01; be = be01; E = 262144.f; base = 9; }
  else if (t < 160) { br = 2; o = t - 96; w = w02; bb = b02; gg = g02; be = be02; E = 524288.f; base = 18; }
  else return;
  const float Sx = mom[base], Sy = mom[base + 1], Sz = mom[base + 2];
  const float mxx = mom[base + 3], mxy = mom[base + 4], mxz = mom[base + 5];
  const float myy = mom[base + 6], myz = mom[base + 7], mzz = mom[base + 8];
  const float W0 = w[o * 3], W1 = w[o * 3 + 1], W2 = w[o * 3 + 2], bo = bb[o];
  const float wS = W0 * Sx + W1 * Sy + W2 * Sz;
  const float qf = W0 * W0 * mxx + 2.f * W0 * W1 * mxy + 2.f * W0 * W2 * mxz
                 + W1 * W1 * myy + 2.f * W1 * W2 * myz + W2 * W2 * mzz;
  const float mean = wS / E + bo;
  const float msq = (qf + 2.f * bo * wS) / E + bo * bo;
  const float var = msq - mean * mean;
  const float inv = 1.0f / sqrtf(var + 1e-5f);
  const float sc = gg[o] * inv;
  scsh[br * 768 + o] = sc;
  scsh[br * 768 + 128 + o] = be[o] - mean * sc;
}

// ---------------------------------------------------------------- reduce 512 partial rows -> 32 (width 768)
__global__ __launch_bounds__(256) void reduce_rows_kernel(const float* __restrict__ partials,
                                                          float* __restrict__ out32) {
  const int r0 = blockIdx.x;
  for (int j = threadIdx.x; j < 768; j += 256) {
    float s = 0.f;
    for (int r = r0 * 16; r < r0 * 16 + 16; ++r) s += partials[(size_t)r * 768 + j];
    out32[r0 * 768 + j] = s;
  }
}

// ---------------------------------------------------------------- BN1 finalize (all 3 branches)
__global__ __launch_bounds__(256) void finalizeA_kernel(const float* __restrict__ p2,
    const float* __restrict__ g1, const float* __restrict__ be1,
    const float* __restrict__ g2, const float* __restrict__ be2,
    const float* __restrict__ g3, const float* __restrict__ be3,
    float* __restrict__ scsh) {
  const int t = threadIdx.x;
  int br, o;
  if (t < 32)       { br = 0; o = t; }
  else if (t < 96)  { br = 1; o = t - 32; }
  else if (t < 192) { br = 2; o = t - 96; }
  else return;
  const int base = (br == 0) ? 0 : (br == 1) ? 64 : 192;
  const float E = (br == 0) ? 131072.f : (br == 1) ? 262144.f : 524288.f;
  const float* g  = (br == 0) ? g1 : (br == 1) ? g2 : g3;
  const float* be = (br == 0) ? be1 : (br == 1) ? be2 : be3;
  const int cs = base + ((o >> 5) << 6) + 2 * (o & 31);
  float sm = 0.f, sq = 0.f;
  for (int r = 0; r < 32; ++r) { sm += p2[r * 768 + cs]; sq += p2[r * 768 + cs + 1]; }
  const float mean = sm / E;
  const float var = sq / E - mean * mean;
  const float inv = 1.0f / sqrtf(var + 1e-5f);
  const float sc = g[o] * inv;
  scsh[br * 768 + 256 + o] = sc;
  scsh[br * 768 + 384 + o] = be[o] - mean * sc;
}

// ---------------------------------------------------------------- BN2 finalize (all 3 branches)
__global__ __launch_bounds__(512) void finalizeB_kernel(const float* __restrict__ p2,
    const float* __restrict__ g1, const float* __restrict__ be1,
    const float* __restrict__ g2, const float* __restrict__ be2,
    const float* __restrict__ g3, const float* __restrict__ be3,
    float* __restrict__ scsh) {
  const int t = threadIdx.x;
  int br, o;
  if (t < 64)       { br = 0; o = t; }
  else if (t < 192) { br = 1; o = t - 64; }
  else if (t < 320) { br = 2; o = t - 192; }
  else return;
  const int base = (br == 0) ? 0 : (br == 1) ? 128 : 384;
  const float E = (br == 0) ? 131072.f : (br == 1) ? 262144.f : 524288.f;
  const float* g  = (br == 0) ? g1 : (br == 1) ? g2 : g3;
  const float* be = (br == 0) ? be1 : (br == 1) ? be2 : be3;
  const int cs = base + ((o >> 5) << 6) + 2 * (o & 31);
  float sm = 0.f, sq = 0.f;
  for (int r = 0; r < 32; ++r) { sm += p2[r * 768 + cs]; sq += p2[r * 768 + cs + 1]; }
  const float mean = sm / E;
  const float var = sq / E - mean * mean;
  const float inv = 1.0f / sqrtf(var + 1e-5f);
  const float sc = g[o] * inv;
  scsh[br * 768 + 512 + o] = sc;
  scsh[br * 768 + 640 + o] = be[o] - mean * sc;
}

// ---------------------------------------------------------------- pass1 branch body
template<int C0, int C1, int T, int X1OFF, int SOFF>
DEVFN void p1_branch(int tid, int pt, float zx, float zy, float zz, float m,
                     const float* __restrict__ w0, const float* __restrict__ b0,
                     const v2h* __restrict__ w1p, const float* __restrict__ b1,
                     const float* __restrict__ scshb,
                     float* spart, float* prow, __half2* __restrict__ x1h2) {
  constexpr int C02 = C0 / 2;
  const float* sc0 = scshb;
  const float* sh0 = scshb + 128;
  v2h a0p[C02];
  #pragma unroll
  for (int c2 = 0; c2 < C02; ++c2) {
    float va = b0[2 * c2]     + zx * w0[6 * c2]     + zy * w0[6 * c2 + 1] + zz * w0[6 * c2 + 2];
    float vb = b0[2 * c2 + 1] + zx * w0[6 * c2 + 3] + zy * w0[6 * c2 + 4] + zz * w0[6 * c2 + 5];
    va = fmaxf(0.f, va * sc0[2 * c2] + sh0[2 * c2]);
    vb = fmaxf(0.f, vb * sc0[2 * c2 + 1] + sh0[2 * c2 + 1]);
    a0p[c2] = v2h{(_Float16)va, (_Float16)vb};
  }
  #pragma unroll
  for (int CB = 0; CB < C1; CB += 32) {
    float arr[32];
    #pragma unroll
    for (int oo = 0; oo < 32; ++oo) {
      const int o = CB + oo;
      float s0 = 0.f, s1 = 0.f;
      #pragma unroll
      for (int c2 = 0; c2 < C02; c2 += 2) {
        s0 = fdot2(a0p[c2],     w1p[o * C02 + c2],     s0);
        s1 = fdot2(a0p[c2 + 1], w1p[o * C02 + c2 + 1], s1);
      }
      arr[oo] = b1[o] + (s0 + s1);
    }
    #pragma unroll
    for (int j = 0; j < 16; ++j)
      x1h2[(size_t)(X1OFF + CB / 2 + j) * 65536 + pt] = __floats2half2_rn(arr[2 * j], arr[2 * j + 1]);
    do_stats_w<32, 32, T>(arr, m, tid, spart, prow, SOFF + (CB / 32) * 64);
  }
}

// ---------------------------------------------------------------- pass1all (3 branches)
template<int T>
__global__ __launch_bounds__(T) void pass1all_kernel(
    const float* __restrict__ pts, const int* __restrict__ cnt,
    const float* __restrict__ w0a, const float* __restrict__ b0a,
    const v2h* __restrict__ w1pa, const float* __restrict__ b1a,
    const float* __restrict__ w0b, const float* __restrict__ b0b,
    const v2h* __restrict__ w1pb, const float* __restrict__ b1b,
    const float* __restrict__ w0c, const float* __restrict__ b0c,
    const v2h* __restrict__ w1pc, const float* __restrict__ b1c,
    const float* __restrict__ scsh, float* __restrict__ partials,
    __half2* __restrict__ x1h2) {
  __shared__ float spart[(T / 64) * 256];
  const int tid = threadIdx.x;
  const int pt = blockIdx.x * T + tid;
  const float* pp = pts + (size_t)pt * 3;
  const float zx = pp[0], zy = pp[1], zz = pp[2];
  float* prow = partials + (size_t)blockIdx.x * 768;
  p1_branch<32, 32, T, 0, 0>(tid, pt, zx, zy, zz, (float)cnt[pt],
      w0a, b0a, w1pa, b1a, scsh, spart, prow, x1h2);
  p1_branch<64, 64, T, 16, 64>(tid, pt, zx, zy, zz, (float)cnt[65536 + pt],
      w0b, b0b, w1pb, b1b, scsh + 768, spart, prow, x1h2);
  p1_branch<64, 96, T, 48, 192>(tid, pt, zx, zy, zz, (float)cnt[131072 + pt],
      w0c, b0c, w1pc, b1c, scsh + 1536, spart, prow, x1h2);
}

// ---------------------------------------------------------------- pass2 branch body
template<int C1, int C2, int T, int X1OFF, int SOFF>
DEVFN void p2_branch(int tid, int pt, float m, const __half2* __restrict__ x1h2,
                     const v2h* __restrict__ w2p, const float* __restrict__ b2,
                     const float* __restrict__ scshb, v2h* arowv,
                     float* spart, float* prow, __half2* __restrict__ x2out) {
  constexpr int C12 = C1 / 2;
  constexpr int RSv = C12 + 1;
  constexpr int CP = C2 / 2;
  const float* sc1 = scshb + 256;
  const float* sh1 = scshb + 384;
  v2h* myrow = arowv + tid * RSv;
  for (int o2 = 0; o2 < C12; ++o2) {
    const float2 f = __half22float2(x1h2[(size_t)(X1OFF + o2) * 65536 + pt]);
    const float xa = fmaxf(0.f, f.x * sc1[2 * o2] + sh1[2 * o2]);
    const float xb = fmaxf(0.f, f.y * sc1[2 * o2 + 1] + sh1[2 * o2 + 1]);
    myrow[o2] = v2h{(_Float16)xa, (_Float16)xb};
  }
  #pragma unroll
  for (int CB = 0; CB < C2; CB += 32) {
    float acc[32];
    #pragma unroll
    for (int j = 0; j < 32; ++j) acc[j] = b2[CB + j];
    for (int c2 = 0; c2 < C12; ++c2) {
      const v2h az = myrow[c2];
      const v2h* wrow = w2p + c2 * C2 + CB;
      #pragma unroll
      for (int j = 0; j < 32; ++j) acc[j] = fdot2(az, wrow[j], acc[j]);
    }
    #pragma unroll
    for (int j = 0; j < 16; ++j)
      x2out[(size_t)pt * CP + CB / 2 + j] = __floats2half2_rn(acc[2 * j], acc[2 * j + 1]);
    do_stats_w<32, 32, T>(acc, m, tid, spart, prow, SOFF + (CB / 32) * 64);
  }
}

// ---------------------------------------------------------------- pass2all (3 branches)
template<int T>
__global__ __launch_bounds__(T) void pass2all_kernel(
    const __half2* __restrict__ x1h2, const int* __restrict__ cnt,
    const v2h* __restrict__ w2pa, const float* __restrict__ b2a,
    const v2h* __restrict__ w2pb, const float* __restrict__ b2b,
    const v2h* __restrict__ w2pc, const float* __restrict__ b2c,
    const float* __restrict__ scsh, float* __restrict__ partials,
    __half2* __restrict__ x2h2) {
  __shared__ v2h arowv[T * 49];
  __shared__ float spart[(T / 64) * 256];
  const int tid = threadIdx.x;
  const int pt = blockIdx.x * T + tid;
  float* prow = partials + (size_t)blockIdx.x * 768;
  p2_branch<32, 64, T, 0, 0>(tid, pt, (float)cnt[pt], x1h2,
      w2pa, b2a, scsh, arowv, spart, prow, x2h2);
  p2_branch<64, 128, T, 16, 128>(tid, pt, (float)cnt[65536 + pt], x1h2,
      w2pb, b2b, scsh + 768, arowv, spart, prow, x2h2 + (size_t)65536 * 32);
  p2_branch<96, 128, T, 48, 384>(tid, pt, (float)cnt[131072 + pt], x1h2,
      w2pc, b2c, scsh + 1536, arowv, spart, prow, x2h2 + (size_t)65536 * 96);
}

// ---------------------------------------------------------------- pool (all 3 branches)
__global__ __launch_bounds__(256) void poolall_kernel(const __half2* __restrict__ x2h2,
                                                      const int* __restrict__ knn_,
                                                      const float* __restrict__ scsh,
                                                      float* __restrict__ out) {
  const int gid = blockIdx.x * 256 + threadIdx.x;
  int K, CP, s, cp, boff;
  const __half2* xb; const float* scb;
  if (gid < 262144) {                       // b1: 8192 x 32 pairs
    K = 16; CP = 32; s = gid >> 5; cp = gid & 31;
    xb = x2h2; scb = scsh; boff = 0;
  } else if (gid < 786432) {                // b2: 8192 x 64 pairs
    const int l = gid - 262144;
    K = 32; CP = 64; s = l >> 6; cp = l & 63;
    xb = x2h2 + (size_t)65536 * 32; scb = scsh + 768; boff = 64;
  } else {                                  // b3: 8192 x 64 pairs
    const int l = gid - 786432;
    K = 64; CP = 64; s = l >> 6; cp = l & 63;
    xb = x2h2 + (size_t)65536 * 96; scb = scsh + 1536; boff = 192;
  }
  const int b = s >> 10;
  const int* kn = knn_ + s * 64;
  float mx0 = -1e30f, mx1 = -1e30f, mn0 = 1e30f, mn1 = 1e30f;
  #pragma unroll 8
  for (int k = 0; k < K; ++k) {
    const int idx = kn[k];
    const float2 f = __half22float2(xb[(size_t)(b * 8192 + idx) * CP + cp]);
    mx0 = fmaxf(mx0, f.x); mn0 = fminf(mn0, f.x);
    mx1 = fmaxf(mx1, f.y); mn1 = fminf(mn1, f.y);
  }
  const float sca = scb[512 + 2 * cp], sccb = scb[512 + 2 * cp + 1];
  const float sha = scb[640 + 2 * cp], shb = scb[640 + 2 * cp + 1];
  float2 r;
  r.x = fmaxf(0.f, fmaf(sca, (sca >= 0.f) ? mx0 : mn0, sha));
  r.y = fmaxf(0.f, fmaf(sccb, (sccb >= 0.f) ? mx1 : mn1, shb));
  *(float2*)&out[(size_t)s * 320 + boff + 2 * cp] = r;
}

// ---------------------------------------------------------------- host side
extern "C" void kernel_launch(void* const* d_in, const int* in_sizes, int n_in,
                              void* d_out, int out_size, void* d_ws, size_t ws_size,
                              hipStream_t stream) {
  (void)in_sizes; (void)n_in; (void)out_size; (void)ws_size;
  const float* pts = (const float*)d_in[0];
  const float* W_[9]; const float* B_[9]; const float* G_[9]; const float* BE_[9];
  for (int m = 0; m < 9; ++m) {
    W_[m]  = (const float*)d_in[1 + m * 4 + 0];
    B_[m]  = (const float*)d_in[1 + m * 4 + 1];
    G_[m]  = (const float*)d_in[1 + m * 4 + 2];
    BE_[m] = (const float*)d_in[1 + m * 4 + 3];
  }
  char* ws = (char*)d_ws;
  float4*  cent     = (float4*)ws;                          // @0,        131072 B
  int*     knn_     = (int*)(ws + 131072);                  // 2 MB
  float*   partials = (float*)(ws + 2228224);               // 512 x 768 x 4 (also mpart)
  float*   scsh     = (float*)(ws + 6422528);               // 12 KB
  v2h*     w1h2     = (v2h*)(ws + 6434816);                 // 22528 B
  v2h*     w2h2     = (v2h*)(ws + 6457344);                 // 45056 B
  float*   partials2= (float*)(ws + 6502400);               // 96 KB
  int*     cnt      = (int*)(ws + 6600704);                 // 786432 B
  float4*  pts4     = (float4*)(ws + 7387136);              // 1 MB
  __half2* x1h2     = (__half2*)(ws + 8435712);             // 24 MB
  __half2* x2h2     = (__half2*)(ws + 33601536);            // 40 MB
  float*   out      = (float*)d_out;

  prep_kernel<<<768, 256, 0, stream>>>(pts, cnt, pts4,
      W_[1], W_[4], W_[7], W_[2], W_[5], W_[8], w1h2, w2h2);
  fps_kernel<<<8, 512, 0, stream>>>(pts, cent);
  knn_kernel<<<2048, 256, 0, stream>>>(pts4, pts, cent, knn_, cnt, partials);
  finalize0_kernel<<<1, 256, 0, stream>>>(partials,
      W_[0], B_[0], G_[0], BE_[0], W_[3], B_[3], G_[3], BE_[3],
      W_[6], B_[6], G_[6], BE_[6], scsh);

  constexpr int T = 128;
  pass1all_kernel<T><<<65536 / T, T, 0, stream>>>(
      pts, cnt, W_[0], B_[0], w1h2, B_[1], W_[3], B_[3], w1h2 + 512, B_[4],
      W_[6], B_[6], w1h2 + 2560, B_[7], scsh, partials, x1h2);
  reduce_rows_kernel<<<32, 256, 0, stream>>>(partials, partials2);
  finalizeA_kernel<<<1, 256, 0, stream>>>(partials2, G_[1], BE_[1], G_[4], BE_[4],
                                          G_[7], BE_[7], scsh);
  pass2all_kernel<T><<<65536 / T, T, 0, stream>>>(
      x1h2, cnt, w2h2, B_[2], w2h2 + 1024, B_[5], w2h2 + 5120, B_[8],
      scsh, partials, x2h2);
  reduce_rows_kernel<<<32, 256, 0, stream>>>(partials, partials2);
  finalizeB_kernel<<<1, 512, 0, stream>>>(partials2, G_[2], BE_[2], G_[5], BE_[5],
                                          G_[8], BE_[8], scsh);
  poolall_kernel<<<5120, 256, 0, stream>>>(x2h2, knn_, scsh, out);
}